// Round 8
// baseline (297.000 us; speedup 1.0000x reference)
//
#include <hip/hip_runtime.h>
#include <cstdint>
#include <cstddef>

// ---------------- problem constants ----------------
#define BB 4
#define SS 2048
#define EE 512
#define HH 8
#define DD 64
#define MM (BB*SS)                       // 8192 token rows
#define BHSD ((size_t)BB*HH*SS*DD)       // 4194304 elements per q/k/v head tensor

static constexpr float SCALE_INV = 1.0f / 181.0f;   // SCALE = float(512 // 8**0.5) = 181.0
static constexpr float LN_EPS = 1e-5f;

typedef float  v4f  __attribute__((ext_vector_type(4)));
typedef __bf16 v8bf __attribute__((ext_vector_type(8)));
typedef __bf16 v4bf __attribute__((ext_vector_type(4)));
typedef short  s4   __attribute__((ext_vector_type(4)));

static __device__ __forceinline__ v4f mfma16(v8bf a, v8bf b, v4f c) {
  return __builtin_amdgcn_mfma_f32_16x16x32_bf16(a, b, c, 0, 0, 0);
}
// K=16 bf16 MFMA via BUILTIN (compiler models MFMA hazards; the inline-asm form
// NaN'd under rescheduling in rounds 6/7 -- never hand-emit MFMA in asm here).
// Fragment layout (HW-verified in round 5): A row=l15, k=4*lg+j ; B col=l15,
// k=4*lg+j ; C/D col=l15, row=4*lg+reg.
static __device__ __forceinline__ v4f mfma16x16(v4bf a, v4bf b, v4f c) {
  s4 ai = __builtin_bit_cast(s4, a);
  s4 bi = __builtin_bit_cast(s4, b);
  return __builtin_amdgcn_mfma_f32_16x16x16bf16_1k(ai, bi, c, 0, 0, 0);
}

// ---------------- workspace layout (bytes) ----------------
// Xb  bf16 [3][M][E]       : 25165824   (q,k,v inputs as bf16)
// Wb  bf16 [4][E][E]       :  2097152   (Wq,Wk,Wv,Wo as bf16)
// Xh  bf16: q [B][H][S][D], k [B][H][S][D], vT [B][H][D][S]   : 25165824
// AO  bf16 [M][E]          :  8388608   (attention output, merged heads)
// maskF f32 [3][M]         :    98304
static constexpr size_t oXb = 0;
static constexpr size_t oWb = oXb + (size_t)3*MM*EE*2;
static constexpr size_t oXh = oWb + (size_t)4*EE*EE*2;
static constexpr size_t oAO = oXh + (size_t)3*MM*EE*2;
static constexpr size_t oMk = oAO + (size_t)MM*EE*2;

// ================= mask canonicalization =================
__global__ void mask_kernel(const void* qm, const void* km, const void* vm, float* maskF) {
  __shared__ int s_n01, s_nF;
  const int t = threadIdx.x;
  if (t == 0) { s_n01 = 0; s_nF = 0; }
  __syncthreads();
  int n01 = 0, nF = 0;
  const unsigned* wq = (const unsigned*)qm;
  for (int i = t; i < 2048; i += 256) {
    const unsigned u = wq[i];
    if (u != 0u && u != 1u) n01 = 1;
    if (u != 0u && u != 0x3F800000u) nF = 1;
  }
  if (n01) atomicOr(&s_n01, 1);
  if (nF)  atomicOr(&s_nF, 1);
  __syncthreads();
  const int mode = (!s_n01) ? 0 : (!s_nF) ? 1 : 2;   // 0=i32, 1=f32, 2=u8
  for (int m = 0; m < 3; ++m) {
    const void* p = (m == 0) ? qm : (m == 1) ? km : vm;
    for (int i = t; i < MM; i += 256) {
      int v;
      if (mode == 0)      v = (((const int*)p)[i] != 0);
      else if (mode == 1) v = (((const unsigned*)p)[i] != 0u);
      else                v = (((const unsigned char*)p)[i] != 0);
      maskF[m*MM + i] = v ? 1.0f : 0.0f;
    }
  }
}

// ================= fp32 -> bf16 convert =================
__global__ void convert_kernel(const float* q, const float* k, const float* v,
                               const float* Wq, const float* Wk, const float* Wv, const float* Wo,
                               __bf16* Xb, __bf16* Wb) {
  const long idx = (long)blockIdx.x * 256 + threadIdx.x;     // in float4 units
  const long NX4 = (long)3*MM*EE/4;
  const long NW4 = (long)4*EE*EE/4;
  if (idx < NX4) {
    const long per = (long)MM*EE/4;
    const long mat = idx / per, off = idx % per;
    const float* src = (mat == 0) ? q : (mat == 1) ? k : v;
    v4f val = ((const v4f*)src)[off];
    v4bf o; o[0]=(__bf16)val[0]; o[1]=(__bf16)val[1]; o[2]=(__bf16)val[2]; o[3]=(__bf16)val[3];
    ((v4bf*)Xb)[idx] = o;
  } else if (idx < NX4 + NW4) {
    const long j = idx - NX4;
    const long per = (long)EE*EE/4;
    const long mat = j / per, off = j % per;
    const float* src = (mat == 0) ? Wq : (mat == 1) ? Wk : (mat == 2) ? Wv : Wo;
    v4f val = ((const v4f*)src)[off];
    v4bf o; o[0]=(__bf16)val[0]; o[1]=(__bf16)val[1]; o[2]=(__bf16)val[2]; o[3]=(__bf16)val[3];
    ((v4bf*)Wb)[j] = o;
  }
}

// ===== projection GEMM + bias + mask + per-head LayerNorm, fused =====
// mat 0 (q), 1 (k): Xh region row-major [B][H][S][D].
// mat 2 (v): written TRANSPOSED per head: [B][H][D][S] (for barrier-free attn PV).
__global__ __launch_bounds__(256) void gemm_proj_ln(const __bf16* Xb, const __bf16* Wb,
                                                    const float* bq, const float* bk, const float* bv,
                                                    const float* gq, const float* betaq,
                                                    const float* gk, const float* betak,
                                                    const float* gv, const float* betav,
                                                    const float* maskF, __bf16* Xh) {
  const int m0  = blockIdx.x * 128;
  const int n0  = blockIdx.y * 128;
  const int mat = blockIdx.z;
  const __bf16* A = Xb + (size_t)mat*MM*EE;
  const __bf16* W = Wb + (size_t)mat*EE*EE;
  const float* bias = (mat == 0) ? bq : (mat == 1) ? bk : bv;
  const float* gam  = (mat == 0) ? gq : (mat == 1) ? gk : gv;
  const float* bet  = (mat == 0) ? betaq : (mat == 1) ? betak : betav;

  __shared__ __bf16 As[128*32];   // [row][k], 64B rows, 4-slot XOR swizzle
  __shared__ __bf16 Bs[128*32];

  const int t = threadIdx.x;
  const int lane = t & 63, w = t >> 6;
  const int wm = w >> 1, wn = w & 1;
  const int l15 = lane & 15, lg = lane >> 4;

  v4f acc[4][4];
  const v4f zf = {0.f, 0.f, 0.f, 0.f};
#pragma unroll
  for (int i = 0; i < 4; ++i)
#pragma unroll
    for (int j = 0; j < 4; ++j) acc[i][j] = zf;

  const int sr  = t >> 1;
  const int sc0 = (t & 1) * 2;

  for (int kt = 0; kt < EE; kt += 32) {
    const __bf16* ga = A + (size_t)(m0 + sr)*EE + kt + sc0*8;
    const __bf16* gb = W + (size_t)(n0 + sr)*EE + kt + sc0*8;
#pragma unroll
    for (int i = 0; i < 2; ++i) {
      const int c = sc0 + i;
      const int dst = sr*64 + ((c*16) ^ ((sr & 3) << 4));
      *(v8bf*)((char*)As + dst) = *(const v8bf*)((const char*)ga + i*16);
      *(v8bf*)((char*)Bs + dst) = *(const v8bf*)((const char*)gb + i*16);
    }
    __syncthreads();
    v8bf afr[4], bfr[4];
#pragma unroll
    for (int i = 0; i < 4; ++i) {
      const int ra = wm*64 + i*16 + l15;
      afr[i] = *(const v8bf*)((const char*)As + ra*64 + ((16*lg) ^ ((ra & 3) << 4)));
      const int rb = wn*64 + i*16 + l15;
      bfr[i] = *(const v8bf*)((const char*)Bs + rb*64 + ((16*lg) ^ ((rb & 3) << 4)));
    }
#pragma unroll
    for (int i = 0; i < 4; ++i)
#pragma unroll
      for (int j = 0; j < 4; ++j)
        acc[i][j] = mfma16(afr[i], bfr[j], acc[i][j]);
    __syncthreads();
  }

  // ---- fused epilogue: bias, mask, per-head LN, bf16 store ----
  const int nbase = n0 + wn*64;          // 64-aligned => one head
  const int h = nbase >> 6;
  float bsv[4], gmv[4], btv[4];
#pragma unroll
  for (int j = 0; j < 4; ++j) {
    const int d = j*16 + l15;
    bsv[j] = bias[nbase + d];
    gmv[j] = gam[d];
    btv[j] = bet[d];
  }
#pragma unroll
  for (int i = 0; i < 4; ++i)
#pragma unroll
    for (int rr = 0; rr < 4; ++rr) {
      const int row = m0 + wm*64 + i*16 + 4*lg + rr;
      const float mv = maskF[mat*MM + row];
      float x[4];
      float s = 0.f, s2 = 0.f;
#pragma unroll
      for (int j = 0; j < 4; ++j) {
        x[j] = (acc[i][j][rr] + bsv[j]) * mv;
        s += x[j]; s2 += x[j]*x[j];
      }
      s  += __shfl_xor(s, 1, 64);  s  += __shfl_xor(s, 2, 64);
      s  += __shfl_xor(s, 4, 64);  s  += __shfl_xor(s, 8, 64);
      s2 += __shfl_xor(s2, 1, 64); s2 += __shfl_xor(s2, 2, 64);
      s2 += __shfl_xor(s2, 4, 64); s2 += __shfl_xor(s2, 8, 64);
      const float mu  = s * (1.0f/64.0f);
      const float var = s2 * (1.0f/64.0f) - mu*mu;
      const float rstd = rsqrtf(var + LN_EPS);
      const int bidx = row >> 11, sI = row & 2047;
      if (mat == 2) {
        // V^T layout: [B][H][D][S]
        const size_t vbase = 2*BHSD + (((size_t)bidx*HH + h)*DD)*SS;
#pragma unroll
        for (int j = 0; j < 4; ++j)
          Xh[vbase + (size_t)(j*16 + l15)*SS + sI] = (__bf16)((x[j] - mu)*rstd*gmv[j] + btv[j]);
      } else {
        const size_t base = (size_t)mat*BHSD + (((size_t)bidx*HH + h)*SS + sI)*DD;
#pragma unroll
        for (int j = 0; j < 4; ++j)
          Xh[base + j*16 + l15] = (__bf16)((x[j] - mu)*rstd*gmv[j] + btv[j]);
      }
    }
}

// ================= flash attention, LDS/barrier-free =================
// grid (S/32, H, B); block = 1 wave; wave owns 32 q rows; launch_bounds(64,2) -> 256 VGPR
// so a whole tile's 28 loads batch-issue (round-5 at 96 VGPR serialized them).
// Swapped QK^T: st = mfma(K,Q) -> lane holds q=l15, keys f*16+4lg+rr -- exactly the
// 16x16x16 A-frag layout, so PV needs no cross-lane traffic. V read from V^T [B][H][D][S].
__global__ __launch_bounds__(64, 2) void attn_kernel(const __bf16* Xh, const float* maskF, __bf16* AO) {
  const int qb = blockIdx.x, h = blockIdx.y, b = blockIdx.z;
  const int lane = threadIdx.x & 63;
  const int l15 = lane & 15, lg = lane >> 4;

  const size_t headoff = (((size_t)b*HH + h)*SS)*DD;
  const __bf16* Qg = Xh + headoff;
  const __bf16* Kg = Xh + BHSD + headoff;
  const __bf16* Vt = Xh + 2*BHSD + (((size_t)b*HH + h)*DD)*SS;   // [D][S]
  const float* qmF = maskF + (size_t)b*SS;
  const float* kmF = maskF + MM + (size_t)b*SS;

  const int q0 = qb*32;

  // Q fragments, pre-scaled by 1/181 (softmax shift-invariance; bf16 rounding only)
  v8bf qf[2][2];
#pragma unroll
  for (int m = 0; m < 2; ++m)
#pragma unroll
    for (int kd = 0; kd < 2; ++kd) {
      v8bf r = *(const v8bf*)(Qg + (size_t)(q0 + m*16 + l15)*DD + kd*32 + lg*8);
      v8bf o;
#pragma unroll
      for (int e = 0; e < 8; ++e) o[e] = (__bf16)((float)r[e] * SCALE_INV);
      qf[m][kd] = o;
    }

  v4f O[2][4];
  float mrun[2], lrun[2];
  const v4f zf = {0.f,0.f,0.f,0.f};
#pragma unroll
  for (int m = 0; m < 2; ++m) {
    mrun[m] = -INFINITY; lrun[m] = 0.f;
#pragma unroll
    for (int df = 0; df < 4; ++df) O[m][df] = zf;
  }

  for (int kt0 = 0; kt0 < SS; kt0 += 64) {
    // ---- loads for this tile (batched; 256-VGPR cap lets all stay in flight) ----
    v8bf kf[4][2];
#pragma unroll
    for (int f = 0; f < 4; ++f)
#pragma unroll
      for (int kd = 0; kd < 2; ++kd)
        kf[f][kd] = *(const v8bf*)(Kg + (size_t)(kt0 + f*16 + l15)*DD + kd*32 + lg*8);
    v4bf vf[4][4];
#pragma unroll
    for (int f = 0; f < 4; ++f)
#pragma unroll
      for (int df = 0; df < 4; ++df)
        vf[f][df] = *(const v4bf*)(Vt + (size_t)(df*16 + l15)*SS + kt0 + f*16 + 4*lg);
    v4f km4[4];
#pragma unroll
    for (int f = 0; f < 4; ++f)
      km4[f] = *(const v4f*)(kmF + kt0 + f*16 + 4*lg);

    // ---- S^T = K Q^T : lane: q=l15, key=f*16+4*lg+rr ----
    v4f st[2][4];
#pragma unroll
    for (int m = 0; m < 2; ++m)
#pragma unroll
      for (int f = 0; f < 4; ++f) st[m][f] = zf;
#pragma unroll
    for (int kd = 0; kd < 2; ++kd)
#pragma unroll
      for (int f = 0; f < 4; ++f)
#pragma unroll
        for (int m = 0; m < 2; ++m)
          st[m][f] = mfma16(kf[f][kd], qf[m][kd], st[m][f]);

    // ---- online softmax, fully in-register ----
#pragma unroll
    for (int m = 0; m < 2; ++m) {
      float p[4][4];
      float pmax = -3e38f;
#pragma unroll
      for (int f = 0; f < 4; ++f)
#pragma unroll
        for (int rr = 0; rr < 4; ++rr) {
          const float sv = (km4[f][rr] > 0.5f) ? st[m][f][rr] : -1e9f;
          p[f][rr] = sv;
          pmax = fmaxf(pmax, sv);
        }
      pmax = fmaxf(pmax, __shfl_xor(pmax, 16, 64));
      pmax = fmaxf(pmax, __shfl_xor(pmax, 32, 64));
      const float mnew = fmaxf(mrun[m], pmax);
      const float corr = __expf(mrun[m] - mnew);
      mrun[m] = mnew;
      float lt = 0.f;
#pragma unroll
      for (int f = 0; f < 4; ++f)
#pragma unroll
        for (int rr = 0; rr < 4; ++rr) {
          const float e = __expf(p[f][rr] - mnew);
          p[f][rr] = e;
          lt += e;
        }
      lt += __shfl_xor(lt, 16, 64);
      lt += __shfl_xor(lt, 32, 64);
      lrun[m] = lrun[m]*corr + lt;
      // O rescale: O rows are q=4*lg+rr; stats live at q=l15 -> broadcast via shfl
#pragma unroll
      for (int rr = 0; rr < 4; ++rr) {
        const float corrO = __shfl(corr, (lg << 4) | (4*lg + rr), 64);
        O[m][0][rr] *= corrO; O[m][1][rr] *= corrO;
        O[m][2][rr] *= corrO; O[m][3][rr] *= corrO;
      }
      // ---- PV: P per-lane layout == 16x16x16 A-frag (k = 4*lg+0..3) ----
#pragma unroll
      for (int f = 0; f < 4; ++f) {
        v4bf pa;
        pa[0] = (__bf16)p[f][0]; pa[1] = (__bf16)p[f][1];
        pa[2] = (__bf16)p[f][2]; pa[3] = (__bf16)p[f][3];
#pragma unroll
        for (int df = 0; df < 4; ++df)
          O[m][df] = mfma16x16(pa, vf[f][df], O[m][df]);
      }
    }
  }

  // ---- epilogue: 1/l, query mask, store ----
#pragma unroll
  for (int m = 0; m < 2; ++m)
#pragma unroll
    for (int rr = 0; rr < 4; ++rr) {
      const float lr = __shfl(lrun[m], (lg << 4) | (4*lg + rr), 64);
      const int qrow = q0 + m*16 + 4*lg + rr;
      const float scl = qmF[qrow] / lr;
#pragma unroll
      for (int df = 0; df < 4; ++df)
        AO[(size_t)(b*SS + qrow)*EE + h*DD + df*16 + l15] = (__bf16)(O[m][df][rr] * scl);
    }
}

// ================= output GEMM: out = (AO @ Wo^T + bo) * qmask =================
__global__ __launch_bounds__(256) void gemm_out(const __bf16* AO, const __bf16* Wb,
                                                const float* bo, const float* maskF, float* out) {
  const int m0 = blockIdx.x * 128;
  const int n0 = blockIdx.y * 128;
  const __bf16* A = AO;
  const __bf16* W = Wb + (size_t)3*EE*EE;   // Wo

  __shared__ __bf16 As[128*32];
  __shared__ __bf16 Bs[128*32];

  const int t = threadIdx.x;
  const int lane = t & 63, w = t >> 6;
  const int wm = w >> 1, wn = w & 1;
  const int l15 = lane & 15, lg = lane >> 4;

  v4f acc[4][4];
  const v4f zf = {0.f,0.f,0.f,0.f};
#pragma unroll
  for (int i = 0; i < 4; ++i)
#pragma unroll
    for (int j = 0; j < 4; ++j) acc[i][j] = zf;

  const int sr  = t >> 1;
  const int sc0 = (t & 1) * 2;

  for (int kt = 0; kt < EE; kt += 32) {
    const __bf16* ga = A + (size_t)(m0 + sr)*EE + kt + sc0*8;
    const __bf16* gb = W + (size_t)(n0 + sr)*EE + kt + sc0*8;
#pragma unroll
    for (int i = 0; i < 2; ++i) {
      const int c = sc0 + i;
      const int dst = sr*64 + ((c*16) ^ ((sr & 3) << 4));
      *(v8bf*)((char*)As + dst) = *(const v8bf*)((const char*)ga + i*16);
      *(v8bf*)((char*)Bs + dst) = *(const v8bf*)((const char*)gb + i*16);
    }
    __syncthreads();
    v8bf afr[4], bfr[4];
#pragma unroll
    for (int i = 0; i < 4; ++i) {
      const int ra = wm*64 + i*16 + l15;
      afr[i] = *(const v8bf*)((const char*)As + ra*64 + ((16*lg) ^ ((ra & 3) << 4)));
      const int rb = wn*64 + i*16 + l15;
      bfr[i] = *(const v8bf*)((const char*)Bs + rb*64 + ((16*lg) ^ ((rb & 3) << 4)));
    }
#pragma unroll
    for (int i = 0; i < 4; ++i)
#pragma unroll
      for (int j = 0; j < 4; ++j)
        acc[i][j] = mfma16(afr[i], bfr[j], acc[i][j]);
    __syncthreads();
  }

  float bsv[4]; int ncol[4];
#pragma unroll
  for (int j = 0; j < 4; ++j) {
    ncol[j] = n0 + wn*64 + j*16 + l15;
    bsv[j] = bo[ncol[j]];
  }
#pragma unroll
  for (int i = 0; i < 4; ++i)
#pragma unroll
    for (int rr = 0; rr < 4; ++rr) {
      const int row = m0 + wm*64 + i*16 + 4*lg + rr;
      const float mv = maskF[row];   // query mask
#pragma unroll
      for (int j = 0; j < 4; ++j)
        out[(size_t)row*EE + ncol[j]] = (acc[i][j][rr] + bsv[j]) * mv;
    }
}

// ================= launcher =================
extern "C" void kernel_launch(void* const* d_in, const int* in_sizes, int n_in,
                              void* d_out, int out_size, void* d_ws, size_t ws_size,
                              hipStream_t stream) {
  const float* q  = (const float*)d_in[0];
  const float* k  = (const float*)d_in[1];
  const float* v  = (const float*)d_in[2];
  const float* Wq = (const float*)d_in[3];
  const float* bq = (const float*)d_in[4];
  const float* Wk = (const float*)d_in[5];
  const float* bk = (const float*)d_in[6];
  const float* Wv = (const float*)d_in[7];
  const float* bv = (const float*)d_in[8];
  const float* Wo = (const float*)d_in[9];
  const float* bo = (const float*)d_in[10];
  const float* gq = (const float*)d_in[11];
  const float* betaq = (const float*)d_in[12];
  const float* gk = (const float*)d_in[13];
  const float* betak = (const float*)d_in[14];
  const float* gv = (const float*)d_in[15];
  const float* betav = (const float*)d_in[16];

  char* ws = (char*)d_ws;
  __bf16* Xb = (__bf16*)(ws + oXb);
  __bf16* Wb = (__bf16*)(ws + oWb);
  __bf16* Xh = (__bf16*)(ws + oXh);
  __bf16* AO = (__bf16*)(ws + oAO);
  float*  maskF = (float*)(ws + oMk);

  mask_kernel<<<dim3(1), dim3(256), 0, stream>>>(d_in[17], d_in[18], d_in[19], maskF);
  convert_kernel<<<dim3(13312), dim3(256), 0, stream>>>(q, k, v, Wq, Wk, Wv, Wo, Xb, Wb);
  gemm_proj_ln<<<dim3(64, 4, 3), dim3(256), 0, stream>>>(Xb, Wb, bq, bk, bv,
                                                         gq, betaq, gk, betak, gv, betav,
                                                         maskF, Xh);
  attn_kernel<<<dim3(64, 8, 4), dim3(64), 0, stream>>>(Xh, maskF, AO);
  gemm_out<<<dim3(64, 4, 1), dim3(256), 0, stream>>>(AO, Wb, bo, maskF, (float*)d_out);
}

// Round 9
// 267.734 us; speedup vs baseline: 1.1093x; 1.1093x over previous
//
#include <hip/hip_runtime.h>
#include <cstdint>
#include <cstddef>

// ---------------- problem constants ----------------
#define BB 4
#define SS 2048
#define EE 512
#define HH 8
#define DD 64
#define MM (BB*SS)                       // 8192 token rows
#define BHSD ((size_t)BB*HH*SS*DD)       // 4194304 elements per q/k/v head tensor

static constexpr float SCALE_INV = 1.0f / 181.0f;   // SCALE = float(512 // 8**0.5) = 181.0
static constexpr float LN_EPS = 1e-5f;

typedef float  v4f  __attribute__((ext_vector_type(4)));
typedef __bf16 v8bf __attribute__((ext_vector_type(8)));
typedef __bf16 v4bf __attribute__((ext_vector_type(4)));
typedef short  s4   __attribute__((ext_vector_type(4)));

static __device__ __forceinline__ v4f mfma16(v8bf a, v8bf b, v4f c) {
  return __builtin_amdgcn_mfma_f32_16x16x32_bf16(a, b, c, 0, 0, 0);
}
// K=16 bf16 MFMA via BUILTIN only (inline-asm MFMA NaN'd under rescheduling, r6/r7).
// Fragment layout (HW-verified r5/r8): A row=l15,k=4lg+j ; B col=l15,k=4lg+j ;
// C/D col=l15,row=4lg+reg.
static __device__ __forceinline__ v4f mfma16x16(v4bf a, v4bf b, v4f c) {
  s4 ai = __builtin_bit_cast(s4, a);
  s4 bi = __builtin_bit_cast(s4, b);
  return __builtin_amdgcn_mfma_f32_16x16x16bf16_1k(ai, bi, c, 0, 0, 0);
}

// ---------------- workspace layout (bytes) ----------------
static constexpr size_t oXb = 0;
static constexpr size_t oWb = oXb + (size_t)3*MM*EE*2;
static constexpr size_t oXh = oWb + (size_t)4*EE*EE*2;
static constexpr size_t oAO = oXh + (size_t)3*MM*EE*2;
static constexpr size_t oMk = oAO + (size_t)MM*EE*2;

// ================= mask canonicalization (parallel) =================
// Each block re-derives the dtype mode from the first 2048 u32 words (8 KB,
// L2-hot after block 0) -- avoids cross-block communication.
__global__ void mask_kernel(const void* qm, const void* km, const void* vm, float* maskF) {
  __shared__ int s_n01, s_nF;
  const int t = threadIdx.x;
  if (t == 0) { s_n01 = 0; s_nF = 0; }
  __syncthreads();
  int n01 = 0, nF = 0;
  const unsigned* wq = (const unsigned*)qm;
  for (int i = t; i < 2048; i += 256) {
    const unsigned u = wq[i];
    if (u != 0u && u != 1u) n01 = 1;
    if (u != 0u && u != 0x3F800000u) nF = 1;
  }
  if (n01) atomicOr(&s_n01, 1);
  if (nF)  atomicOr(&s_nF, 1);
  __syncthreads();
  const int mode = (!s_n01) ? 0 : (!s_nF) ? 1 : 2;   // 0=i32, 1=f32, 2=u8
  const int gidx = blockIdx.x * 256 + t;              // 0 .. 3*MM-1 (grid 96)
  const int m = gidx / MM, i = gidx % MM;
  const void* p = (m == 0) ? qm : (m == 1) ? km : vm;
  int v;
  if (mode == 0)      v = (((const int*)p)[i] != 0);
  else if (mode == 1) v = (((const unsigned*)p)[i] != 0u);
  else                v = (((const unsigned char*)p)[i] != 0);
  maskF[m*MM + i] = v ? 1.0f : 0.0f;
}

// ================= fp32 -> bf16 convert =================
__global__ void convert_kernel(const float* q, const float* k, const float* v,
                               const float* Wq, const float* Wk, const float* Wv, const float* Wo,
                               __bf16* Xb, __bf16* Wb) {
  const long idx = (long)blockIdx.x * 256 + threadIdx.x;     // in float4 units
  const long NX4 = (long)3*MM*EE/4;
  const long NW4 = (long)4*EE*EE/4;
  if (idx < NX4) {
    const long per = (long)MM*EE/4;
    const long mat = idx / per, off = idx % per;
    const float* src = (mat == 0) ? q : (mat == 1) ? k : v;
    v4f val = ((const v4f*)src)[off];
    v4bf o; o[0]=(__bf16)val[0]; o[1]=(__bf16)val[1]; o[2]=(__bf16)val[2]; o[3]=(__bf16)val[3];
    ((v4bf*)Xb)[idx] = o;
  } else if (idx < NX4 + NW4) {
    const long j = idx - NX4;
    const long per = (long)EE*EE/4;
    const long mat = j / per, off = j % per;
    const float* src = (mat == 0) ? Wq : (mat == 1) ? Wk : (mat == 2) ? Wv : Wo;
    v4f val = ((const v4f*)src)[off];
    v4bf o; o[0]=(__bf16)val[0]; o[1]=(__bf16)val[1]; o[2]=(__bf16)val[2]; o[3]=(__bf16)val[3];
    ((v4bf*)Wb)[j] = o;
  }
}

// ===== projection GEMM + bias + mask + per-head LayerNorm, fused =====
// mat 0 (q), 1 (k): Xh region row-major [B][H][S][D].
// mat 2 (v): written TRANSPOSED per head: [B][H][D][S].
__global__ __launch_bounds__(256) void gemm_proj_ln(const __bf16* Xb, const __bf16* Wb,
                                                    const float* bq, const float* bk, const float* bv,
                                                    const float* gq, const float* betaq,
                                                    const float* gk, const float* betak,
                                                    const float* gv, const float* betav,
                                                    const float* maskF, __bf16* Xh) {
  const int m0  = blockIdx.x * 128;
  const int n0  = blockIdx.y * 128;
  const int mat = blockIdx.z;
  const __bf16* A = Xb + (size_t)mat*MM*EE;
  const __bf16* W = Wb + (size_t)mat*EE*EE;
  const float* bias = (mat == 0) ? bq : (mat == 1) ? bk : bv;
  const float* gam  = (mat == 0) ? gq : (mat == 1) ? gk : gv;
  const float* bet  = (mat == 0) ? betaq : (mat == 1) ? betak : betav;

  __shared__ __bf16 As[128*32];   // [row][k], 64B rows, 4-slot XOR swizzle
  __shared__ __bf16 Bs[128*32];

  const int t = threadIdx.x;
  const int lane = t & 63, w = t >> 6;
  const int wm = w >> 1, wn = w & 1;
  const int l15 = lane & 15, lg = lane >> 4;

  v4f acc[4][4];
  const v4f zf = {0.f, 0.f, 0.f, 0.f};
#pragma unroll
  for (int i = 0; i < 4; ++i)
#pragma unroll
    for (int j = 0; j < 4; ++j) acc[i][j] = zf;

  const int sr  = t >> 1;
  const int sc0 = (t & 1) * 2;

  for (int kt = 0; kt < EE; kt += 32) {
    const __bf16* ga = A + (size_t)(m0 + sr)*EE + kt + sc0*8;
    const __bf16* gb = W + (size_t)(n0 + sr)*EE + kt + sc0*8;
#pragma unroll
    for (int i = 0; i < 2; ++i) {
      const int c = sc0 + i;
      const int dst = sr*64 + ((c*16) ^ ((sr & 3) << 4));
      *(v8bf*)((char*)As + dst) = *(const v8bf*)((const char*)ga + i*16);
      *(v8bf*)((char*)Bs + dst) = *(const v8bf*)((const char*)gb + i*16);
    }
    __syncthreads();
    v8bf afr[4], bfr[4];
#pragma unroll
    for (int i = 0; i < 4; ++i) {
      const int ra = wm*64 + i*16 + l15;
      afr[i] = *(const v8bf*)((const char*)As + ra*64 + ((16*lg) ^ ((ra & 3) << 4)));
      const int rb = wn*64 + i*16 + l15;
      bfr[i] = *(const v8bf*)((const char*)Bs + rb*64 + ((16*lg) ^ ((rb & 3) << 4)));
    }
#pragma unroll
    for (int i = 0; i < 4; ++i)
#pragma unroll
      for (int j = 0; j < 4; ++j)
        acc[i][j] = mfma16(afr[i], bfr[j], acc[i][j]);
    __syncthreads();
  }

  // ---- fused epilogue: bias, mask, per-head LN, bf16 store ----
  const int nbase = n0 + wn*64;          // 64-aligned => one head
  const int h = nbase >> 6;
  float bsv[4], gmv[4], btv[4];
#pragma unroll
  for (int j = 0; j < 4; ++j) {
    const int d = j*16 + l15;
    bsv[j] = bias[nbase + d];
    gmv[j] = gam[d];
    btv[j] = bet[d];
  }
#pragma unroll
  for (int i = 0; i < 4; ++i)
#pragma unroll
    for (int rr = 0; rr < 4; ++rr) {
      const int row = m0 + wm*64 + i*16 + 4*lg + rr;
      const float mv = maskF[mat*MM + row];
      float x[4];
      float s = 0.f, s2 = 0.f;
#pragma unroll
      for (int j = 0; j < 4; ++j) {
        x[j] = (acc[i][j][rr] + bsv[j]) * mv;
        s += x[j]; s2 += x[j]*x[j];
      }
      s  += __shfl_xor(s, 1, 64);  s  += __shfl_xor(s, 2, 64);
      s  += __shfl_xor(s, 4, 64);  s  += __shfl_xor(s, 8, 64);
      s2 += __shfl_xor(s2, 1, 64); s2 += __shfl_xor(s2, 2, 64);
      s2 += __shfl_xor(s2, 4, 64); s2 += __shfl_xor(s2, 8, 64);
      const float mu  = s * (1.0f/64.0f);
      const float var = s2 * (1.0f/64.0f) - mu*mu;
      const float rstd = rsqrtf(var + LN_EPS);
      const int bidx = row >> 11, sI = row & 2047;
      if (mat == 2) {
        const size_t vbase = 2*BHSD + (((size_t)bidx*HH + h)*DD)*SS;
#pragma unroll
        for (int j = 0; j < 4; ++j)
          Xh[vbase + (size_t)(j*16 + l15)*SS + sI] = (__bf16)((x[j] - mu)*rstd*gmv[j] + btv[j]);
      } else {
        const size_t base = (size_t)mat*BHSD + (((size_t)bidx*HH + h)*SS + sI)*DD;
#pragma unroll
        for (int j = 0; j < 4; ++j)
          Xh[base + j*16 + l15] = (__bf16)((x[j] - mu)*rstd*gmv[j] + btv[j]);
      }
    }
}

// ================= flash attention: fixed-max softmax + intra-block key-split =================
// grid (S/32, H, B); block = 256 (4 waves). All 4 waves own the SAME 32 q-rows;
// wave w handles key tiles (4i+w)*64. Fixed-max softmax (LN bounds |S|<=~22 so
// exp is fp32-safe; masked keys become p=0 via multiply) -> NO cross-lane ops in
// the loop, and partials combine by plain summation in LDS.
// Swapped QK^T: lane holds q=l15, key=f*16+4lg+rr == the 16x16x16 A-frag layout.
__global__ __launch_bounds__(256) void attn_kernel(const __bf16* Xh, const float* maskF, __bf16* AO) {
  const int qb = blockIdx.x, h = blockIdx.y, b = blockIdx.z;
  const int t = threadIdx.x;
  const int w = t >> 6, lane = t & 63;
  const int l15 = lane & 15, lg = lane >> 4;

  __shared__ float Of[4][32][64];   // per-wave partial O
  __shared__ float Lf[4][32];       // per-wave partial l

  const size_t headoff = (((size_t)b*HH + h)*SS)*DD;
  const __bf16* Qg = Xh + headoff;
  const __bf16* Kg = Xh + BHSD + headoff;
  const __bf16* Vt = Xh + 2*BHSD + (((size_t)b*HH + h)*DD)*SS;   // [D][S]
  const float* qmF = maskF + (size_t)b*SS;
  const float* kmF = maskF + MM + (size_t)b*SS;

  const int q0 = qb*32;

  // Q fragments, pre-scaled by 1/181 (softmax shift-invariance; bf16 rounding only)
  v8bf qf[2][2];
#pragma unroll
  for (int m = 0; m < 2; ++m)
#pragma unroll
    for (int kd = 0; kd < 2; ++kd) {
      v8bf r = *(const v8bf*)(Qg + (size_t)(q0 + m*16 + l15)*DD + kd*32 + lg*8);
      v8bf o;
#pragma unroll
      for (int e = 0; e < 8; ++e) o[e] = (__bf16)((float)r[e] * SCALE_INV);
      qf[m][kd] = o;
    }

  v4f O[2][4];
  float lsum[2] = {0.f, 0.f};
  const v4f zf = {0.f,0.f,0.f,0.f};
#pragma unroll
  for (int m = 0; m < 2; ++m)
#pragma unroll
    for (int df = 0; df < 4; ++df) O[m][df] = zf;

  for (int i = 0; i < 8; ++i) {
    const int kt0 = (4*i + w) * 64;
    // ---- loads for this tile ----
    v8bf kf[4][2];
#pragma unroll
    for (int f = 0; f < 4; ++f)
#pragma unroll
      for (int kd = 0; kd < 2; ++kd)
        kf[f][kd] = *(const v8bf*)(Kg + (size_t)(kt0 + f*16 + l15)*DD + kd*32 + lg*8);
    v4bf vf[4][4];
#pragma unroll
    for (int f = 0; f < 4; ++f)
#pragma unroll
      for (int df = 0; df < 4; ++df)
        vf[f][df] = *(const v4bf*)(Vt + (size_t)(df*16 + l15)*SS + kt0 + f*16 + 4*lg);
    v4f km4[4];
#pragma unroll
    for (int f = 0; f < 4; ++f)
      km4[f] = *(const v4f*)(kmF + kt0 + f*16 + 4*lg);

    // ---- S^T = K Q^T : lane: q=l15, key=f*16+4*lg+rr ----
    v4f st[2][4];
#pragma unroll
    for (int m = 0; m < 2; ++m)
#pragma unroll
      for (int f = 0; f < 4; ++f) st[m][f] = zf;
#pragma unroll
    for (int kd = 0; kd < 2; ++kd)
#pragma unroll
      for (int f = 0; f < 4; ++f)
#pragma unroll
        for (int m = 0; m < 2; ++m)
          st[m][f] = mfma16(kf[f][kd], qf[m][kd], st[m][f]);

    // ---- fixed-max softmax: p = exp(s) * km  (no cross-lane ops) ----
#pragma unroll
    for (int m = 0; m < 2; ++m) {
#pragma unroll
      for (int f = 0; f < 4; ++f) {
        float p[4];
#pragma unroll
        for (int rr = 0; rr < 4; ++rr) {
          p[rr] = __expf(st[m][f][rr]) * km4[f][rr];
          lsum[m] += p[rr];
        }
        v4bf pa;
        pa[0] = (__bf16)p[0]; pa[1] = (__bf16)p[1];
        pa[2] = (__bf16)p[2]; pa[3] = (__bf16)p[3];
#pragma unroll
        for (int df = 0; df < 4; ++df)
          O[m][df] = mfma16x16(pa, vf[f][df], O[m][df]);
      }
    }
  }

  // ---- per-wave l reduce (q=l15 across lg groups), write partials to LDS ----
#pragma unroll
  for (int m = 0; m < 2; ++m) {
    lsum[m] += __shfl_xor(lsum[m], 16, 64);
    lsum[m] += __shfl_xor(lsum[m], 32, 64);
  }
  if (lg == 0) { Lf[w][l15] = lsum[0]; Lf[w][16 + l15] = lsum[1]; }
#pragma unroll
  for (int m = 0; m < 2; ++m)
#pragma unroll
    for (int df = 0; df < 4; ++df)
#pragma unroll
      for (int rr = 0; rr < 4; ++rr)
        Of[w][m*16 + 4*lg + rr][df*16 + l15] = O[m][df][rr];
  __syncthreads();

  // ---- combine: thread t -> q = t>>3, d = (t&7)*8 .. +8 ----
  const int q = t >> 3, d0 = (t & 7) * 8;
  float l = Lf[0][q] + Lf[1][q] + Lf[2][q] + Lf[3][q];
  l = fmaxf(l, 1e-30f);
  const float scl = qmF[q0 + q] / l;
  v8bf o;
#pragma unroll
  for (int j = 0; j < 8; ++j) {
    const float s = Of[0][q][d0+j] + Of[1][q][d0+j] + Of[2][q][d0+j] + Of[3][q][d0+j];
    o[j] = (__bf16)(s * scl);
  }
  *(v8bf*)(AO + (size_t)(b*SS + q0 + q)*EE + h*DD + d0) = o;
}

// ================= output GEMM: out = (AO @ Wo^T + bo) * qmask =================
__global__ __launch_bounds__(256) void gemm_out(const __bf16* AO, const __bf16* Wb,
                                                const float* bo, const float* maskF, float* out) {
  const int m0 = blockIdx.x * 128;
  const int n0 = blockIdx.y * 128;
  const __bf16* A = AO;
  const __bf16* W = Wb + (size_t)3*EE*EE;   // Wo

  __shared__ __bf16 As[128*32];
  __shared__ __bf16 Bs[128*32];

  const int t = threadIdx.x;
  const int lane = t & 63, w = t >> 6;
  const int wm = w >> 1, wn = w & 1;
  const int l15 = lane & 15, lg = lane >> 4;

  v4f acc[4][4];
  const v4f zf = {0.f,0.f,0.f,0.f};
#pragma unroll
  for (int i = 0; i < 4; ++i)
#pragma unroll
    for (int j = 0; j < 4; ++j) acc[i][j] = zf;

  const int sr  = t >> 1;
  const int sc0 = (t & 1) * 2;

  for (int kt = 0; kt < EE; kt += 32) {
    const __bf16* ga = A + (size_t)(m0 + sr)*EE + kt + sc0*8;
    const __bf16* gb = W + (size_t)(n0 + sr)*EE + kt + sc0*8;
#pragma unroll
    for (int i = 0; i < 2; ++i) {
      const int c = sc0 + i;
      const int dst = sr*64 + ((c*16) ^ ((sr & 3) << 4));
      *(v8bf*)((char*)As + dst) = *(const v8bf*)((const char*)ga + i*16);
      *(v8bf*)((char*)Bs + dst) = *(const v8bf*)((const char*)gb + i*16);
    }
    __syncthreads();
    v8bf afr[4], bfr[4];
#pragma unroll
    for (int i = 0; i < 4; ++i) {
      const int ra = wm*64 + i*16 + l15;
      afr[i] = *(const v8bf*)((const char*)As + ra*64 + ((16*lg) ^ ((ra & 3) << 4)));
      const int rb = wn*64 + i*16 + l15;
      bfr[i] = *(const v8bf*)((const char*)Bs + rb*64 + ((16*lg) ^ ((rb & 3) << 4)));
    }
#pragma unroll
    for (int i = 0; i < 4; ++i)
#pragma unroll
      for (int j = 0; j < 4; ++j)
        acc[i][j] = mfma16(afr[i], bfr[j], acc[i][j]);
    __syncthreads();
  }

  float bsv[4]; int ncol[4];
#pragma unroll
  for (int j = 0; j < 4; ++j) {
    ncol[j] = n0 + wn*64 + j*16 + l15;
    bsv[j] = bo[ncol[j]];
  }
#pragma unroll
  for (int i = 0; i < 4; ++i)
#pragma unroll
    for (int rr = 0; rr < 4; ++rr) {
      const int row = m0 + wm*64 + i*16 + 4*lg + rr;
      const float mv = maskF[row];   // query mask
#pragma unroll
      for (int j = 0; j < 4; ++j)
        out[(size_t)row*EE + ncol[j]] = (acc[i][j][rr] + bsv[j]) * mv;
    }
}

// ================= launcher =================
extern "C" void kernel_launch(void* const* d_in, const int* in_sizes, int n_in,
                              void* d_out, int out_size, void* d_ws, size_t ws_size,
                              hipStream_t stream) {
  const float* q  = (const float*)d_in[0];
  const float* k  = (const float*)d_in[1];
  const float* v  = (const float*)d_in[2];
  const float* Wq = (const float*)d_in[3];
  const float* bq = (const float*)d_in[4];
  const float* Wk = (const float*)d_in[5];
  const float* bk = (const float*)d_in[6];
  const float* Wv = (const float*)d_in[7];
  const float* bv = (const float*)d_in[8];
  const float* Wo = (const float*)d_in[9];
  const float* bo = (const float*)d_in[10];
  const float* gq = (const float*)d_in[11];
  const float* betaq = (const float*)d_in[12];
  const float* gk = (const float*)d_in[13];
  const float* betak = (const float*)d_in[14];
  const float* gv = (const float*)d_in[15];
  const float* betav = (const float*)d_in[16];

  char* ws = (char*)d_ws;
  __bf16* Xb = (__bf16*)(ws + oXb);
  __bf16* Wb = (__bf16*)(ws + oWb);
  __bf16* Xh = (__bf16*)(ws + oXh);
  __bf16* AO = (__bf16*)(ws + oAO);
  float*  maskF = (float*)(ws + oMk);

  mask_kernel<<<dim3(96), dim3(256), 0, stream>>>(d_in[17], d_in[18], d_in[19], maskF);
  convert_kernel<<<dim3(13312), dim3(256), 0, stream>>>(q, k, v, Wq, Wk, Wv, Wo, Xb, Wb);
  gemm_proj_ln<<<dim3(64, 4, 3), dim3(256), 0, stream>>>(Xb, Wb, bq, bk, bv,
                                                         gq, betaq, gk, betak, gv, betav,
                                                         maskF, Xh);
  attn_kernel<<<dim3(64, 8, 4), dim3(256), 0, stream>>>(Xh, maskF, AO);
  gemm_out<<<dim3(64, 4, 1), dim3(256), 0, stream>>>(AO, Wb, bo, maskF, (float*)d_out);
}

// Round 10
// 150.734 us; speedup vs baseline: 1.9704x; 1.7762x over previous
//
#include <hip/hip_runtime.h>
#include <cstdint>
#include <cstddef>

// ---------------- problem constants ----------------
#define BB 4
#define SS 2048
#define EE 512
#define HH 8
#define DD 64
#define MM (BB*SS)                       // 8192 token rows
#define BHSD ((size_t)BB*HH*SS*DD)       // 4194304 elements per q/k/v head tensor

static constexpr float SCALE_INV = 1.0f / 181.0f;   // SCALE = float(512 // 8**0.5) = 181.0
static constexpr float LN_EPS = 1e-5f;

typedef float  v4f  __attribute__((ext_vector_type(4)));
typedef __bf16 v8bf __attribute__((ext_vector_type(8)));
typedef __bf16 v4bf __attribute__((ext_vector_type(4)));
typedef short  s4   __attribute__((ext_vector_type(4)));

static __device__ __forceinline__ v4f mfma16(v8bf a, v8bf b, v4f c) {
  return __builtin_amdgcn_mfma_f32_16x16x32_bf16(a, b, c, 0, 0, 0);
}
// K=16 bf16 MFMA via BUILTIN only (inline-asm MFMA NaN'd under rescheduling, r6/r7).
// Fragment layout (HW-verified r5/r8/r9): A row=l15,k=4lg+j ; B col=l15,k=4lg+j ;
// C/D col=l15,row=4lg+reg.
static __device__ __forceinline__ v4f mfma16x16(v4bf a, v4bf b, v4f c) {
  s4 ai = __builtin_bit_cast(s4, a);
  s4 bi = __builtin_bit_cast(s4, b);
  return __builtin_amdgcn_mfma_f32_16x16x16bf16_1k(ai, bi, c, 0, 0, 0);
}

// async global->LDS, 16B per lane; LDS dest = wave-uniform base + lane*16 (HW rule).
typedef const void __attribute__((address_space(1))) gas_void;
typedef void __attribute__((address_space(3))) las_void;
static __device__ __forceinline__ void gload_lds16(const void* g, void* l) {
  __builtin_amdgcn_global_load_lds((gas_void*)g, (las_void*)l, 16, 0, 0);
}

// ---------------- workspace layout (bytes) ----------------
static constexpr size_t oXb = 0;
static constexpr size_t oWb = oXb + (size_t)3*MM*EE*2;
static constexpr size_t oXh = oWb + (size_t)4*EE*EE*2;
static constexpr size_t oAO = oXh + (size_t)3*MM*EE*2;
static constexpr size_t oMk = oAO + (size_t)MM*EE*2;

// ================= mask canonicalization (parallel) =================
__global__ void mask_kernel(const void* qm, const void* km, const void* vm, float* maskF) {
  __shared__ int s_n01, s_nF;
  const int t = threadIdx.x;
  if (t == 0) { s_n01 = 0; s_nF = 0; }
  __syncthreads();
  int n01 = 0, nF = 0;
  const unsigned* wq = (const unsigned*)qm;
  for (int i = t; i < 2048; i += 256) {
    const unsigned u = wq[i];
    if (u != 0u && u != 1u) n01 = 1;
    if (u != 0u && u != 0x3F800000u) nF = 1;
  }
  if (n01) atomicOr(&s_n01, 1);
  if (nF)  atomicOr(&s_nF, 1);
  __syncthreads();
  const int mode = (!s_n01) ? 0 : (!s_nF) ? 1 : 2;   // 0=i32, 1=f32, 2=u8
  const int gidx = blockIdx.x * 256 + t;
  const int m = gidx / MM, i = gidx % MM;
  const void* p = (m == 0) ? qm : (m == 1) ? km : vm;
  int v;
  if (mode == 0)      v = (((const int*)p)[i] != 0);
  else if (mode == 1) v = (((const unsigned*)p)[i] != 0u);
  else                v = (((const unsigned char*)p)[i] != 0);
  maskF[m*MM + i] = v ? 1.0f : 0.0f;
}

// ================= fp32 -> bf16 convert =================
__global__ void convert_kernel(const float* q, const float* k, const float* v,
                               const float* Wq, const float* Wk, const float* Wv, const float* Wo,
                               __bf16* Xb, __bf16* Wb) {
  const long idx = (long)blockIdx.x * 256 + threadIdx.x;     // in float4 units
  const long NX4 = (long)3*MM*EE/4;
  const long NW4 = (long)4*EE*EE/4;
  if (idx < NX4) {
    const long per = (long)MM*EE/4;
    const long mat = idx / per, off = idx % per;
    const float* src = (mat == 0) ? q : (mat == 1) ? k : v;
    v4f val = ((const v4f*)src)[off];
    v4bf o; o[0]=(__bf16)val[0]; o[1]=(__bf16)val[1]; o[2]=(__bf16)val[2]; o[3]=(__bf16)val[3];
    ((v4bf*)Xb)[idx] = o;
  } else if (idx < NX4 + NW4) {
    const long j = idx - NX4;
    const long per = (long)EE*EE/4;
    const long mat = j / per, off = j % per;
    const float* src = (mat == 0) ? Wq : (mat == 1) ? Wk : (mat == 2) ? Wv : Wo;
    v4f val = ((const v4f*)src)[off];
    v4bf o; o[0]=(__bf16)val[0]; o[1]=(__bf16)val[1]; o[2]=(__bf16)val[2]; o[3]=(__bf16)val[3];
    ((v4bf*)Wb)[j] = o;
  }
}

// ===== projection GEMM + bias + mask + per-head LayerNorm, fused =====
__global__ __launch_bounds__(256) void gemm_proj_ln(const __bf16* Xb, const __bf16* Wb,
                                                    const float* bq, const float* bk, const float* bv,
                                                    const float* gq, const float* betaq,
                                                    const float* gk, const float* betak,
                                                    const float* gv, const float* betav,
                                                    const float* maskF, __bf16* Xh) {
  const int m0  = blockIdx.x * 128;
  const int n0  = blockIdx.y * 128;
  const int mat = blockIdx.z;
  const __bf16* A = Xb + (size_t)mat*MM*EE;
  const __bf16* W = Wb + (size_t)mat*EE*EE;
  const float* bias = (mat == 0) ? bq : (mat == 1) ? bk : bv;
  const float* gam  = (mat == 0) ? gq : (mat == 1) ? gk : gv;
  const float* bet  = (mat == 0) ? betaq : (mat == 1) ? betak : betav;

  __shared__ __bf16 As[128*32];
  __shared__ __bf16 Bs[128*32];

  const int t = threadIdx.x;
  const int lane = t & 63, w = t >> 6;
  const int wm = w >> 1, wn = w & 1;
  const int l15 = lane & 15, lg = lane >> 4;

  v4f acc[4][4];
  const v4f zf = {0.f, 0.f, 0.f, 0.f};
#pragma unroll
  for (int i = 0; i < 4; ++i)
#pragma unroll
    for (int j = 0; j < 4; ++j) acc[i][j] = zf;

  const int sr  = t >> 1;
  const int sc0 = (t & 1) * 2;

  for (int kt = 0; kt < EE; kt += 32) {
    const __bf16* ga = A + (size_t)(m0 + sr)*EE + kt + sc0*8;
    const __bf16* gb = W + (size_t)(n0 + sr)*EE + kt + sc0*8;
#pragma unroll
    for (int i = 0; i < 2; ++i) {
      const int c = sc0 + i;
      const int dst = sr*64 + ((c*16) ^ ((sr & 3) << 4));
      *(v8bf*)((char*)As + dst) = *(const v8bf*)((const char*)ga + i*16);
      *(v8bf*)((char*)Bs + dst) = *(const v8bf*)((const char*)gb + i*16);
    }
    __syncthreads();
    v8bf afr[4], bfr[4];
#pragma unroll
    for (int i = 0; i < 4; ++i) {
      const int ra = wm*64 + i*16 + l15;
      afr[i] = *(const v8bf*)((const char*)As + ra*64 + ((16*lg) ^ ((ra & 3) << 4)));
      const int rb = wn*64 + i*16 + l15;
      bfr[i] = *(const v8bf*)((const char*)Bs + rb*64 + ((16*lg) ^ ((rb & 3) << 4)));
    }
#pragma unroll
    for (int i = 0; i < 4; ++i)
#pragma unroll
      for (int j = 0; j < 4; ++j)
        acc[i][j] = mfma16(afr[i], bfr[j], acc[i][j]);
    __syncthreads();
  }

  const int nbase = n0 + wn*64;          // 64-aligned => one head
  const int h = nbase >> 6;
  float bsv[4], gmv[4], btv[4];
#pragma unroll
  for (int j = 0; j < 4; ++j) {
    const int d = j*16 + l15;
    bsv[j] = bias[nbase + d];
    gmv[j] = gam[d];
    btv[j] = bet[d];
  }
#pragma unroll
  for (int i = 0; i < 4; ++i)
#pragma unroll
    for (int rr = 0; rr < 4; ++rr) {
      const int row = m0 + wm*64 + i*16 + 4*lg + rr;
      const float mv = maskF[mat*MM + row];
      float x[4];
      float s = 0.f, s2 = 0.f;
#pragma unroll
      for (int j = 0; j < 4; ++j) {
        x[j] = (acc[i][j][rr] + bsv[j]) * mv;
        s += x[j]; s2 += x[j]*x[j];
      }
      s  += __shfl_xor(s, 1, 64);  s  += __shfl_xor(s, 2, 64);
      s  += __shfl_xor(s, 4, 64);  s  += __shfl_xor(s, 8, 64);
      s2 += __shfl_xor(s2, 1, 64); s2 += __shfl_xor(s2, 2, 64);
      s2 += __shfl_xor(s2, 4, 64); s2 += __shfl_xor(s2, 8, 64);
      const float mu  = s * (1.0f/64.0f);
      const float var = s2 * (1.0f/64.0f) - mu*mu;
      const float rstd = rsqrtf(var + LN_EPS);
      const int bidx = row >> 11, sI = row & 2047;
      if (mat == 2) {
        const size_t vbase = 2*BHSD + (((size_t)bidx*HH + h)*DD)*SS;
#pragma unroll
        for (int j = 0; j < 4; ++j)
          Xh[vbase + (size_t)(j*16 + l15)*SS + sI] = (__bf16)((x[j] - mu)*rstd*gmv[j] + btv[j]);
      } else {
        const size_t base = (size_t)mat*BHSD + (((size_t)bidx*HH + h)*SS + sI)*DD;
#pragma unroll
        for (int j = 0; j < 4; ++j)
          Xh[base + j*16 + l15] = (__bf16)((x[j] - mu)*rstd*gmv[j] + btv[j]);
      }
    }
}

// ================= flash attention: LDS-staged, dbuf, 8-wave in-block k-split ==========
// grid (16 qb, 8 h, 4 b); block = 512 (8 waves). Block owns 128 q rows.
// Waves 0-3 (half 0) own q-groups 0-3 for EVEN key tiles; waves 4-7 same q-groups
// for ODD key tiles. K/V tiles staged via global_load_lds (16B, dbuf per half);
// LDS chunk-XOR swizzle c^(r&7), applied to SOURCE addr + READ addr (rule: linear dest).
// Fixed-max softmax (r9-proven): p = exp(s)*km, no cross-lane ops in loop.
// Halves combine in LDS at the end (plain sums).
__global__ __launch_bounds__(512, 4) void attn_kernel(const __bf16* Xh, const float* maskF, __bf16* AO) {
  const int qb = blockIdx.x, h = blockIdx.y, b = blockIdx.z;
  const int t = threadIdx.x;
  const int w = t >> 6, lane = t & 63;
  const int hh = w >> 2, wq = w & 3;        // key-half, q-group
  const int l15 = lane & 15, lg = lane >> 4;

  __shared__ char smem[65536];              // [half][buf]{K 8KB, V 8KB} = 4*16KB

  const size_t headoff = (((size_t)b*HH + h)*SS)*DD;
  const __bf16* Qg = Xh + headoff;
  const __bf16* Kg = Xh + BHSD + headoff;
  const __bf16* Vt = Xh + 2*BHSD + (((size_t)b*HH + h)*DD)*SS;   // [D][S]
  const float* qmF = maskF + (size_t)b*SS;
  const float* kmF = maskF + MM + (size_t)b*SS;

  const int q0 = qb*128 + wq*32;

  // Q fragments, pre-scaled by 1/181
  v8bf qf[2][2];
#pragma unroll
  for (int m = 0; m < 2; ++m)
#pragma unroll
    for (int kd = 0; kd < 2; ++kd) {
      v8bf r = *(const v8bf*)(Qg + (size_t)(q0 + m*16 + l15)*DD + kd*32 + lg*8);
      v8bf o;
#pragma unroll
      for (int e = 0; e < 8; ++e) o[e] = (__bf16)((float)r[e] * SCALE_INV);
      qf[m][kd] = o;
    }

  v4f O[2][4];
  float lsum[2] = {0.f, 0.f};
  const v4f zf = {0.f,0.f,0.f,0.f};
#pragma unroll
  for (int m = 0; m < 2; ++m)
#pragma unroll
    for (int df = 0; df < 4; ++df) O[m][df] = zf;

  // stage: this wave stages K rows [wq*16, wq*16+16) and V rows likewise (2 insts each).
  // LDS dest is linear (uniform base + lane*16); global SOURCE chunk is c^(r&7).
  const int srow = lane >> 3;               // 0..7 within 8-row group
  const int sc   = lane & 7;                // chunk 0..7
#define STAGE(BUFC, KT0)                                                                \
  {                                                                                     \
    char* kb_ = (BUFC);                                                                 \
    char* vb_ = (BUFC) + 8192;                                                          \
    _Pragma("unroll")                                                                   \
    for (int j_ = 0; j_ < 2; ++j_) {                                                    \
      const int r0_ = wq*16 + j_*8;                                                     \
      const int r_  = r0_ + srow;                                                       \
      gload_lds16(Kg + (size_t)((KT0) + r_)*DD + ((sc ^ (r_ & 7))*8), kb_ + r0_*128);   \
      gload_lds16(Vt + (size_t)r_*SS + (KT0) + ((sc ^ (r_ & 7))*8),  vb_ + r0_*128);    \
    }                                                                                   \
  }

  char* bufA = smem + hh*32768;
  char* bufB = bufA + 16384;

  STAGE(bufA, (0*2 + hh)*64);
  __syncthreads();

  for (int tt = 0; tt < 16; ++tt) {
    char* cur = (tt & 1) ? bufB : bufA;
    char* nxt = (tt & 1) ? bufA : bufB;
    if (tt + 1 < 16) STAGE(nxt, ((tt+1)*2 + hh)*64);

    const int kt0 = (tt*2 + hh)*64;
    char* kb = cur;
    char* vb = cur + 8192;

    // ---- K fragments from LDS (swizzled read) ----
    v8bf kf[4][2];
#pragma unroll
    for (int f = 0; f < 4; ++f)
#pragma unroll
      for (int kd = 0; kd < 2; ++kd) {
        const int rr = f*16 + l15;
        kf[f][kd] = *(const v8bf*)(kb + rr*128 + (((kd*4 + lg) ^ (rr & 7))*16));
      }

    // ---- S^T = K Q^T ----
    v4f st[2][4];
#pragma unroll
    for (int m = 0; m < 2; ++m)
#pragma unroll
      for (int f = 0; f < 4; ++f) st[m][f] = zf;
#pragma unroll
    for (int kd = 0; kd < 2; ++kd)
#pragma unroll
      for (int f = 0; f < 4; ++f)
#pragma unroll
        for (int m = 0; m < 2; ++m)
          st[m][f] = mfma16(kf[f][kd], qf[m][kd], st[m][f]);

    v4f km4[4];
#pragma unroll
    for (int f = 0; f < 4; ++f)
      km4[f] = *(const v4f*)(kmF + kt0 + f*16 + 4*lg);

    // ---- fixed-max softmax + PV (V frags from LDS, swizzled read) ----
#pragma unroll
    for (int m = 0; m < 2; ++m) {
#pragma unroll
      for (int f = 0; f < 4; ++f) {
        float p[4];
#pragma unroll
        for (int rr = 0; rr < 4; ++rr) {
          p[rr] = __expf(st[m][f][rr]) * km4[f][rr];
          lsum[m] += p[rr];
        }
        v4bf pa;
        pa[0] = (__bf16)p[0]; pa[1] = (__bf16)p[1];
        pa[2] = (__bf16)p[2]; pa[3] = (__bf16)p[3];
#pragma unroll
        for (int df = 0; df < 4; ++df) {
          const int rv = df*16 + l15;
          v4bf vv = *(const v4bf*)(vb + rv*128 + (((2*f + (lg >> 1)) ^ (rv & 7))*16) + (lg & 1)*8);
          O[m][df] = mfma16x16(pa, vv, O[m][df]);
        }
      }
    }
    __syncthreads();   // stage(next) drained; cur's reads done before it's overwritten
  }
#undef STAGE

  // ---- per-wave l reduce: row sum for q=l15 valid in all lanes ----
#pragma unroll
  for (int m = 0; m < 2; ++m) {
    lsum[m] += __shfl_xor(lsum[m], 16, 64);
    lsum[m] += __shfl_xor(lsum[m], 32, 64);
  }

  // ---- combine halves in LDS (overlay on staging buffers; loop ended with barrier) ----
  float (*Pp)[32][65] = (float (*)[32][65])smem;            // [4][32][65] = 33.3KB
  float (*Lp)[32]     = (float (*)[32])(smem + 4*32*65*4);
  if (hh == 1) {
#pragma unroll
    for (int m = 0; m < 2; ++m)
#pragma unroll
      for (int df = 0; df < 4; ++df)
#pragma unroll
        for (int rr = 0; rr < 4; ++rr)
          Pp[wq][m*16 + 4*lg + rr][df*16 + l15] = O[m][df][rr];
    if (lg == 0) { Lp[wq][l15] = lsum[0]; Lp[wq][16 + l15] = lsum[1]; }
  }
  __syncthreads();
  if (hh == 0) {
#pragma unroll
    for (int m = 0; m < 2; ++m) {
      lsum[m] += Lp[wq][m*16 + l15];
#pragma unroll
      for (int df = 0; df < 4; ++df)
#pragma unroll
        for (int rr = 0; rr < 4; ++rr)
          O[m][df][rr] += Pp[wq][m*16 + 4*lg + rr][df*16 + l15];
    }
#pragma unroll
    for (int m = 0; m < 2; ++m)
#pragma unroll
      for (int rr = 0; rr < 4; ++rr) {
        const float lr = __shfl(lsum[m], (lg << 4) | (4*lg + rr), 64);
        const int qrow = q0 + m*16 + 4*lg + rr;
        const float scl = qmF[qrow] / fmaxf(lr, 1e-30f);
#pragma unroll
        for (int df = 0; df < 4; ++df)
          AO[(size_t)(b*SS + qrow)*EE + h*DD + df*16 + l15] = (__bf16)(O[m][df][rr] * scl);
      }
  }
}

// ================= output GEMM: out = (AO @ Wo^T + bo) * qmask =================
__global__ __launch_bounds__(256) void gemm_out(const __bf16* AO, const __bf16* Wb,
                                                const float* bo, const float* maskF, float* out) {
  const int m0 = blockIdx.x * 128;
  const int n0 = blockIdx.y * 128;
  const __bf16* A = AO;
  const __bf16* W = Wb + (size_t)3*EE*EE;   // Wo

  __shared__ __bf16 As[128*32];
  __shared__ __bf16 Bs[128*32];

  const int t = threadIdx.x;
  const int lane = t & 63, w = t >> 6;
  const int wm = w >> 1, wn = w & 1;
  const int l15 = lane & 15, lg = lane >> 4;

  v4f acc[4][4];
  const v4f zf = {0.f,0.f,0.f,0.f};
#pragma unroll
  for (int i = 0; i < 4; ++i)
#pragma unroll
    for (int j = 0; j < 4; ++j) acc[i][j] = zf;

  const int sr  = t >> 1;
  const int sc0 = (t & 1) * 2;

  for (int kt = 0; kt < EE; kt += 32) {
    const __bf16* ga = A + (size_t)(m0 + sr)*EE + kt + sc0*8;
    const __bf16* gb = W + (size_t)(n0 + sr)*EE + kt + sc0*8;
#pragma unroll
    for (int i = 0; i < 2; ++i) {
      const int c = sc0 + i;
      const int dst = sr*64 + ((c*16) ^ ((sr & 3) << 4));
      *(v8bf*)((char*)As + dst) = *(const v8bf*)((const char*)ga + i*16);
      *(v8bf*)((char*)Bs + dst) = *(const v8bf*)((const char*)gb + i*16);
    }
    __syncthreads();
    v8bf afr[4], bfr[4];
#pragma unroll
    for (int i = 0; i < 4; ++i) {
      const int ra = wm*64 + i*16 + l15;
      afr[i] = *(const v8bf*)((const char*)As + ra*64 + ((16*lg) ^ ((ra & 3) << 4)));
      const int rb = wn*64 + i*16 + l15;
      bfr[i] = *(const v8bf*)((const char*)Bs + rb*64 + ((16*lg) ^ ((rb & 3) << 4)));
    }
#pragma unroll
    for (int i = 0; i < 4; ++i)
#pragma unroll
      for (int j = 0; j < 4; ++j)
        acc[i][j] = mfma16(afr[i], bfr[j], acc[i][j]);
    __syncthreads();
  }

  float bsv[4]; int ncol[4];
#pragma unroll
  for (int j = 0; j < 4; ++j) {
    ncol[j] = n0 + wn*64 + j*16 + l15;
    bsv[j] = bo[ncol[j]];
  }
#pragma unroll
  for (int i = 0; i < 4; ++i)
#pragma unroll
    for (int rr = 0; rr < 4; ++rr) {
      const int row = m0 + wm*64 + i*16 + 4*lg + rr;
      const float mv = maskF[row];   // query mask
#pragma unroll
      for (int j = 0; j < 4; ++j)
        out[(size_t)row*EE + ncol[j]] = (acc[i][j][rr] + bsv[j]) * mv;
    }
}

// ================= launcher =================
extern "C" void kernel_launch(void* const* d_in, const int* in_sizes, int n_in,
                              void* d_out, int out_size, void* d_ws, size_t ws_size,
                              hipStream_t stream) {
  const float* q  = (const float*)d_in[0];
  const float* k  = (const float*)d_in[1];
  const float* v  = (const float*)d_in[2];
  const float* Wq = (const float*)d_in[3];
  const float* bq = (const float*)d_in[4];
  const float* Wk = (const float*)d_in[5];
  const float* bk = (const float*)d_in[6];
  const float* Wv = (const float*)d_in[7];
  const float* bv = (const float*)d_in[8];
  const float* Wo = (const float*)d_in[9];
  const float* bo = (const float*)d_in[10];
  const float* gq = (const float*)d_in[11];
  const float* betaq = (const float*)d_in[12];
  const float* gk = (const float*)d_in[13];
  const float* betak = (const float*)d_in[14];
  const float* gv = (const float*)d_in[15];
  const float* betav = (const float*)d_in[16];

  char* ws = (char*)d_ws;
  __bf16* Xb = (__bf16*)(ws + oXb);
  __bf16* Wb = (__bf16*)(ws + oWb);
  __bf16* Xh = (__bf16*)(ws + oXh);
  __bf16* AO = (__bf16*)(ws + oAO);
  float*  maskF = (float*)(ws + oMk);

  mask_kernel<<<dim3(96), dim3(256), 0, stream>>>(d_in[17], d_in[18], d_in[19], maskF);
  convert_kernel<<<dim3(13312), dim3(256), 0, stream>>>(q, k, v, Wq, Wk, Wv, Wo, Xb, Wb);
  gemm_proj_ln<<<dim3(64, 4, 3), dim3(256), 0, stream>>>(Xb, Wb, bq, bk, bv,
                                                         gq, betaq, gk, betak, gv, betav,
                                                         maskF, Xh);
  attn_kernel<<<dim3(16, 8, 4), dim3(512), 0, stream>>>(Xh, maskF, AO);
  gemm_out<<<dim3(64, 4, 1), dim3(256), 0, stream>>>(AO, Wb, bo, maskF, (float*)d_out);
}

// Round 11
// 127.603 us; speedup vs baseline: 2.3275x; 1.1813x over previous
//
#include <hip/hip_runtime.h>
#include <cstdint>
#include <cstddef>

// ---------------- problem constants ----------------
#define BB 4
#define SS 2048
#define EE 512
#define HH 8
#define DD 64
#define MM (BB*SS)                       // 8192 token rows
#define BHSD ((size_t)BB*HH*SS*DD)       // 4194304 elements per q/k/v head tensor

static constexpr float SCALE_INV = 1.0f / 181.0f;   // SCALE = float(512 // 8**0.5) = 181.0
static constexpr float LN_EPS = 1e-5f;

typedef float  v4f  __attribute__((ext_vector_type(4)));
typedef __bf16 v8bf __attribute__((ext_vector_type(8)));
typedef __bf16 v4bf __attribute__((ext_vector_type(4)));
typedef short  s4   __attribute__((ext_vector_type(4)));

static __device__ __forceinline__ v4f mfma16(v8bf a, v8bf b, v4f c) {
  return __builtin_amdgcn_mfma_f32_16x16x32_bf16(a, b, c, 0, 0, 0);
}
// K=16 bf16 MFMA via BUILTIN only (inline-asm MFMA NaN'd under rescheduling, r6/r7).
// Fragment layout (HW-verified r5/r8/r9/r10): A row=l15,k=4lg+j ; B col=l15,k=4lg+j ;
// C/D col=l15,row=4lg+reg.
static __device__ __forceinline__ v4f mfma16x16(v4bf a, v4bf b, v4f c) {
  s4 ai = __builtin_bit_cast(s4, a);
  s4 bi = __builtin_bit_cast(s4, b);
  return __builtin_amdgcn_mfma_f32_16x16x16bf16_1k(ai, bi, c, 0, 0, 0);
}

// async global->LDS, 16B per lane; LDS dest = wave-uniform base + lane*16 (HW rule).
typedef const void __attribute__((address_space(1))) gas_void;
typedef void __attribute__((address_space(3))) las_void;
static __device__ __forceinline__ void gload_lds16(const void* g, void* l) {
  __builtin_amdgcn_global_load_lds((gas_void*)g, (las_void*)l, 16, 0, 0);
}

// ---------------- workspace layout (bytes) ----------------
static constexpr size_t oXb = 0;
static constexpr size_t oWb = oXb + (size_t)3*MM*EE*2;
static constexpr size_t oXh = oWb + (size_t)4*EE*EE*2;
static constexpr size_t oAO = oXh + (size_t)3*MM*EE*2;
static constexpr size_t oMk = oAO + (size_t)MM*EE*2;

// ================= mask canonicalization (parallel) =================
__global__ void mask_kernel(const void* qm, const void* km, const void* vm, float* maskF) {
  __shared__ int s_n01, s_nF;
  const int t = threadIdx.x;
  if (t == 0) { s_n01 = 0; s_nF = 0; }
  __syncthreads();
  int n01 = 0, nF = 0;
  const unsigned* wq = (const unsigned*)qm;
  for (int i = t; i < 2048; i += 256) {
    const unsigned u = wq[i];
    if (u != 0u && u != 1u) n01 = 1;
    if (u != 0u && u != 0x3F800000u) nF = 1;
  }
  if (n01) atomicOr(&s_n01, 1);
  if (nF)  atomicOr(&s_nF, 1);
  __syncthreads();
  const int mode = (!s_n01) ? 0 : (!s_nF) ? 1 : 2;   // 0=i32, 1=f32, 2=u8
  const int gidx = blockIdx.x * 256 + t;
  const int m = gidx / MM, i = gidx % MM;
  const void* p = (m == 0) ? qm : (m == 1) ? km : vm;
  int v;
  if (mode == 0)      v = (((const int*)p)[i] != 0);
  else if (mode == 1) v = (((const unsigned*)p)[i] != 0u);
  else                v = (((const unsigned char*)p)[i] != 0);
  maskF[m*MM + i] = v ? 1.0f : 0.0f;
}

// ================= fp32 -> bf16 convert =================
__global__ void convert_kernel(const float* q, const float* k, const float* v,
                               const float* Wq, const float* Wk, const float* Wv, const float* Wo,
                               __bf16* Xb, __bf16* Wb) {
  const long idx = (long)blockIdx.x * 256 + threadIdx.x;     // in float4 units
  const long NX4 = (long)3*MM*EE/4;
  const long NW4 = (long)4*EE*EE/4;
  if (idx < NX4) {
    const long per = (long)MM*EE/4;
    const long mat = idx / per, off = idx % per;
    const float* src = (mat == 0) ? q : (mat == 1) ? k : v;
    v4f val = ((const v4f*)src)[off];
    v4bf o; o[0]=(__bf16)val[0]; o[1]=(__bf16)val[1]; o[2]=(__bf16)val[2]; o[3]=(__bf16)val[3];
    ((v4bf*)Xb)[idx] = o;
  } else if (idx < NX4 + NW4) {
    const long j = idx - NX4;
    const long per = (long)EE*EE/4;
    const long mat = j / per, off = j % per;
    const float* src = (mat == 0) ? Wq : (mat == 1) ? Wk : (mat == 2) ? Wv : Wo;
    v4f val = ((const v4f*)src)[off];
    v4bf o; o[0]=(__bf16)val[0]; o[1]=(__bf16)val[1]; o[2]=(__bf16)val[2]; o[3]=(__bf16)val[3];
    ((v4bf*)Wb)[j] = o;
  }
}

// ===== projection GEMM + bias + mask + per-head LayerNorm, fused =====
// m97-style 2-phase: global_load_lds width-16, double-buffered LDS, 1 barrier/K-step.
// LDS[r][slot s] = global[r][chunk s^(r&3)] (linear DMA dest, inverse-swizzled source);
// read slot lg^(r&3) recovers chunk lg. mat 2 (v) written TRANSPOSED [B][H][D][S].
__global__ __launch_bounds__(256) void gemm_proj_ln(const __bf16* Xb, const __bf16* Wb,
                                                    const float* bq, const float* bk, const float* bv,
                                                    const float* gq, const float* betaq,
                                                    const float* gk, const float* betak,
                                                    const float* gv, const float* betav,
                                                    const float* maskF, __bf16* Xh) {
  const int m0  = blockIdx.x * 128;
  const int n0  = blockIdx.y * 128;
  const int mat = blockIdx.z;
  const __bf16* A = Xb + (size_t)mat*MM*EE;
  const __bf16* W = Wb + (size_t)mat*EE*EE;
  const float* bias = (mat == 0) ? bq : (mat == 1) ? bk : bv;
  const float* gam  = (mat == 0) ? gq : (mat == 1) ? gk : gv;
  const float* bet  = (mat == 0) ? betaq : (mat == 1) ? betak : betav;

  __shared__ char smem[32768];   // [buf][A 8KB | B 8KB]

  const int t = threadIdx.x;
  const int lane = t & 63, w = t >> 6;
  const int wm = w >> 1, wn = w & 1;
  const int l15 = lane & 15, lg = lane >> 4;

  v4f acc[4][4];
  const v4f zf = {0.f, 0.f, 0.f, 0.f};
#pragma unroll
  for (int i = 0; i < 4; ++i)
#pragma unroll
    for (int j = 0; j < 4; ++j) acc[i][j] = zf;

  // staging geometry: per instr j, this wave covers flat 16B-chunks j*256 + w*64 + lane.
  // row = flat>>2 (4 chunks / 64B row), slot = flat&3; source chunk = slot^(row&3).
  const int sr0 = (w*64 + lane) >> 2;       // row for j=0 (j=1 adds 64)
  const int sct = (w*64 + lane) & 3;        // dest slot
#define STAGE_PL(BUF, KT)                                                                 \
  {                                                                                       \
    char* ab_ = (BUF);                                                                    \
    char* bb_ = (BUF) + 8192;                                                             \
    _Pragma("unroll")                                                                     \
    for (int j_ = 0; j_ < 2; ++j_) {                                                      \
      const int r_ = sr0 + j_*64;                                                         \
      const int c_ = sct ^ (r_ & 3);                                                      \
      gload_lds16(A + (size_t)(m0 + r_)*EE + (KT) + c_*8, ab_ + j_*4096 + w*1024);        \
      gload_lds16(W + (size_t)(n0 + r_)*EE + (KT) + c_*8, bb_ + j_*4096 + w*1024);        \
    }                                                                                     \
  }

  char* buf0 = smem;
  char* buf1 = smem + 16384;

  STAGE_PL(buf0, 0);
  __syncthreads();

  int cur = 0;
  for (int kt = 0; kt < EE; kt += 32) {
    char* cb = cur ? buf1 : buf0;
    char* nb = cur ? buf0 : buf1;
    if (kt + 32 < EE) STAGE_PL(nb, kt + 32);

    const char* As = cb;
    const char* Bs = cb + 8192;
    v8bf afr[4], bfr[4];
#pragma unroll
    for (int i = 0; i < 4; ++i) {
      const int ra = wm*64 + i*16 + l15;
      afr[i] = *(const v8bf*)(As + ra*64 + ((16*lg) ^ ((ra & 3) << 4)));
      const int rb = wn*64 + i*16 + l15;
      bfr[i] = *(const v8bf*)(Bs + rb*64 + ((16*lg) ^ ((rb & 3) << 4)));
    }
#pragma unroll
    for (int i = 0; i < 4; ++i)
#pragma unroll
      for (int j = 0; j < 4; ++j)
        acc[i][j] = mfma16(afr[i], bfr[j], acc[i][j]);
    __syncthreads();    // drains stage(next); protects cb overwrite at t+2
    cur ^= 1;
  }
#undef STAGE_PL

  // ---- fused epilogue: bias, mask, per-head LN, bf16 store ----
  const int nbase = n0 + wn*64;          // 64-aligned => one head
  const int h = nbase >> 6;
  float bsv[4], gmv[4], btv[4];
#pragma unroll
  for (int j = 0; j < 4; ++j) {
    const int d = j*16 + l15;
    bsv[j] = bias[nbase + d];
    gmv[j] = gam[d];
    btv[j] = bet[d];
  }
#pragma unroll
  for (int i = 0; i < 4; ++i)
#pragma unroll
    for (int rr = 0; rr < 4; ++rr) {
      const int row = m0 + wm*64 + i*16 + 4*lg + rr;
      const float mv = maskF[mat*MM + row];
      float x[4];
      float s = 0.f, s2 = 0.f;
#pragma unroll
      for (int j = 0; j < 4; ++j) {
        x[j] = (acc[i][j][rr] + bsv[j]) * mv;
        s += x[j]; s2 += x[j]*x[j];
      }
      s  += __shfl_xor(s, 1, 64);  s  += __shfl_xor(s, 2, 64);
      s  += __shfl_xor(s, 4, 64);  s  += __shfl_xor(s, 8, 64);
      s2 += __shfl_xor(s2, 1, 64); s2 += __shfl_xor(s2, 2, 64);
      s2 += __shfl_xor(s2, 4, 64); s2 += __shfl_xor(s2, 8, 64);
      const float mu  = s * (1.0f/64.0f);
      const float var = s2 * (1.0f/64.0f) - mu*mu;
      const float rstd = rsqrtf(var + LN_EPS);
      const int bidx = row >> 11, sI = row & 2047;
      if (mat == 2) {
        const size_t vbase = 2*BHSD + (((size_t)bidx*HH + h)*DD)*SS;
#pragma unroll
        for (int j = 0; j < 4; ++j)
          Xh[vbase + (size_t)(j*16 + l15)*SS + sI] = (__bf16)((x[j] - mu)*rstd*gmv[j] + btv[j]);
      } else {
        const size_t base = (size_t)mat*BHSD + (((size_t)bidx*HH + h)*SS + sI)*DD;
#pragma unroll
        for (int j = 0; j < 4; ++j)
          Xh[base + j*16 + l15] = (__bf16)((x[j] - mu)*rstd*gmv[j] + btv[j]);
      }
    }
}

// ================= flash attention: LDS-staged, dbuf, 8-wave in-block k-split ==========
// (unchanged from round 10 -- passing at 72 us)
__global__ __launch_bounds__(512, 4) void attn_kernel(const __bf16* Xh, const float* maskF, __bf16* AO) {
  const int qb = blockIdx.x, h = blockIdx.y, b = blockIdx.z;
  const int t = threadIdx.x;
  const int w = t >> 6, lane = t & 63;
  const int hh = w >> 2, wq = w & 3;        // key-half, q-group
  const int l15 = lane & 15, lg = lane >> 4;

  __shared__ char smem[65536];              // [half][buf]{K 8KB, V 8KB} = 4*16KB

  const size_t headoff = (((size_t)b*HH + h)*SS)*DD;
  const __bf16* Qg = Xh + headoff;
  const __bf16* Kg = Xh + BHSD + headoff;
  const __bf16* Vt = Xh + 2*BHSD + (((size_t)b*HH + h)*DD)*SS;   // [D][S]
  const float* qmF = maskF + (size_t)b*SS;
  const float* kmF = maskF + MM + (size_t)b*SS;

  const int q0 = qb*128 + wq*32;

  v8bf qf[2][2];
#pragma unroll
  for (int m = 0; m < 2; ++m)
#pragma unroll
    for (int kd = 0; kd < 2; ++kd) {
      v8bf r = *(const v8bf*)(Qg + (size_t)(q0 + m*16 + l15)*DD + kd*32 + lg*8);
      v8bf o;
#pragma unroll
      for (int e = 0; e < 8; ++e) o[e] = (__bf16)((float)r[e] * SCALE_INV);
      qf[m][kd] = o;
    }

  v4f O[2][4];
  float lsum[2] = {0.f, 0.f};
  const v4f zf = {0.f,0.f,0.f,0.f};
#pragma unroll
  for (int m = 0; m < 2; ++m)
#pragma unroll
    for (int df = 0; df < 4; ++df) O[m][df] = zf;

  const int srow = lane >> 3;
  const int sc   = lane & 7;
#define STAGE(BUFC, KT0)                                                                \
  {                                                                                     \
    char* kb_ = (BUFC);                                                                 \
    char* vb_ = (BUFC) + 8192;                                                          \
    _Pragma("unroll")                                                                   \
    for (int j_ = 0; j_ < 2; ++j_) {                                                    \
      const int r0_ = wq*16 + j_*8;                                                     \
      const int r_  = r0_ + srow;                                                       \
      gload_lds16(Kg + (size_t)((KT0) + r_)*DD + ((sc ^ (r_ & 7))*8), kb_ + r0_*128);   \
      gload_lds16(Vt + (size_t)r_*SS + (KT0) + ((sc ^ (r_ & 7))*8),  vb_ + r0_*128);    \
    }                                                                                   \
  }

  char* bufA = smem + hh*32768;
  char* bufB = bufA + 16384;

  STAGE(bufA, (0*2 + hh)*64);
  __syncthreads();

  for (int tt = 0; tt < 16; ++tt) {
    char* cur = (tt & 1) ? bufB : bufA;
    char* nxt = (tt & 1) ? bufA : bufB;
    if (tt + 1 < 16) STAGE(nxt, ((tt+1)*2 + hh)*64);

    const int kt0 = (tt*2 + hh)*64;
    char* kb = cur;
    char* vb = cur + 8192;

    v8bf kf[4][2];
#pragma unroll
    for (int f = 0; f < 4; ++f)
#pragma unroll
      for (int kd = 0; kd < 2; ++kd) {
        const int rr = f*16 + l15;
        kf[f][kd] = *(const v8bf*)(kb + rr*128 + (((kd*4 + lg) ^ (rr & 7))*16));
      }

    v4f st[2][4];
#pragma unroll
    for (int m = 0; m < 2; ++m)
#pragma unroll
      for (int f = 0; f < 4; ++f) st[m][f] = zf;
#pragma unroll
    for (int kd = 0; kd < 2; ++kd)
#pragma unroll
      for (int f = 0; f < 4; ++f)
#pragma unroll
        for (int m = 0; m < 2; ++m)
          st[m][f] = mfma16(kf[f][kd], qf[m][kd], st[m][f]);

    v4f km4[4];
#pragma unroll
    for (int f = 0; f < 4; ++f)
      km4[f] = *(const v4f*)(kmF + kt0 + f*16 + 4*lg);

#pragma unroll
    for (int m = 0; m < 2; ++m) {
#pragma unroll
      for (int f = 0; f < 4; ++f) {
        float p[4];
#pragma unroll
        for (int rr = 0; rr < 4; ++rr) {
          p[rr] = __expf(st[m][f][rr]) * km4[f][rr];
          lsum[m] += p[rr];
        }
        v4bf pa;
        pa[0] = (__bf16)p[0]; pa[1] = (__bf16)p[1];
        pa[2] = (__bf16)p[2]; pa[3] = (__bf16)p[3];
#pragma unroll
        for (int df = 0; df < 4; ++df) {
          const int rv = df*16 + l15;
          v4bf vv = *(const v4bf*)(vb + rv*128 + (((2*f + (lg >> 1)) ^ (rv & 7))*16) + (lg & 1)*8);
          O[m][df] = mfma16x16(pa, vv, O[m][df]);
        }
      }
    }
    __syncthreads();
  }
#undef STAGE

#pragma unroll
  for (int m = 0; m < 2; ++m) {
    lsum[m] += __shfl_xor(lsum[m], 16, 64);
    lsum[m] += __shfl_xor(lsum[m], 32, 64);
  }

  float (*Pp)[32][65] = (float (*)[32][65])smem;            // [4][32][65] = 33.3KB
  float (*Lp)[32]     = (float (*)[32])(smem + 4*32*65*4);
  if (hh == 1) {
#pragma unroll
    for (int m = 0; m < 2; ++m)
#pragma unroll
      for (int df = 0; df < 4; ++df)
#pragma unroll
        for (int rr = 0; rr < 4; ++rr)
          Pp[wq][m*16 + 4*lg + rr][df*16 + l15] = O[m][df][rr];
    if (lg == 0) { Lp[wq][l15] = lsum[0]; Lp[wq][16 + l15] = lsum[1]; }
  }
  __syncthreads();
  if (hh == 0) {
#pragma unroll
    for (int m = 0; m < 2; ++m) {
      lsum[m] += Lp[wq][m*16 + l15];
#pragma unroll
      for (int df = 0; df < 4; ++df)
#pragma unroll
        for (int rr = 0; rr < 4; ++rr)
          O[m][df][rr] += Pp[wq][m*16 + 4*lg + rr][df*16 + l15];
    }
#pragma unroll
    for (int m = 0; m < 2; ++m)
#pragma unroll
      for (int rr = 0; rr < 4; ++rr) {
        const float lr = __shfl(lsum[m], (lg << 4) | (4*lg + rr), 64);
        const int qrow = q0 + m*16 + 4*lg + rr;
        const float scl = qmF[qrow] / fmaxf(lr, 1e-30f);
#pragma unroll
        for (int df = 0; df < 4; ++df)
          AO[(size_t)(b*SS + qrow)*EE + h*DD + df*16 + l15] = (__bf16)(O[m][df][rr] * scl);
      }
  }
}

// ================= output GEMM: out = (AO @ Wo^T + bo) * qmask =================
// same m97-style 2-phase staging as gemm_proj_ln.
__global__ __launch_bounds__(256) void gemm_out(const __bf16* AO, const __bf16* Wb,
                                                const float* bo, const float* maskF, float* out) {
  const int m0 = blockIdx.x * 128;
  const int n0 = blockIdx.y * 128;
  const __bf16* A = AO;
  const __bf16* W = Wb + (size_t)3*EE*EE;   // Wo

  __shared__ char smem[32768];

  const int t = threadIdx.x;
  const int lane = t & 63, w = t >> 6;
  const int wm = w >> 1, wn = w & 1;
  const int l15 = lane & 15, lg = lane >> 4;

  v4f acc[4][4];
  const v4f zf = {0.f,0.f,0.f,0.f};
#pragma unroll
  for (int i = 0; i < 4; ++i)
#pragma unroll
    for (int j = 0; j < 4; ++j) acc[i][j] = zf;

  const int sr0 = (w*64 + lane) >> 2;
  const int sct = (w*64 + lane) & 3;
#define STAGE_PL(BUF, KT)                                                                 \
  {                                                                                       \
    char* ab_ = (BUF);                                                                    \
    char* bb_ = (BUF) + 8192;                                                             \
    _Pragma("unroll")                                                                     \
    for (int j_ = 0; j_ < 2; ++j_) {                                                      \
      const int r_ = sr0 + j_*64;                                                         \
      const int c_ = sct ^ (r_ & 3);                                                      \
      gload_lds16(A + (size_t)(m0 + r_)*EE + (KT) + c_*8, ab_ + j_*4096 + w*1024);        \
      gload_lds16(W + (size_t)(n0 + r_)*EE + (KT) + c_*8, bb_ + j_*4096 + w*1024);        \
    }                                                                                     \
  }

  char* buf0 = smem;
  char* buf1 = smem + 16384;

  STAGE_PL(buf0, 0);
  __syncthreads();

  int cur = 0;
  for (int kt = 0; kt < EE; kt += 32) {
    char* cb = cur ? buf1 : buf0;
    char* nb = cur ? buf0 : buf1;
    if (kt + 32 < EE) STAGE_PL(nb, kt + 32);

    const char* As = cb;
    const char* Bs = cb + 8192;
    v8bf afr[4], bfr[4];
#pragma unroll
    for (int i = 0; i < 4; ++i) {
      const int ra = wm*64 + i*16 + l15;
      afr[i] = *(const v8bf*)(As + ra*64 + ((16*lg) ^ ((ra & 3) << 4)));
      const int rb = wn*64 + i*16 + l15;
      bfr[i] = *(const v8bf*)(Bs + rb*64 + ((16*lg) ^ ((rb & 3) << 4)));
    }
#pragma unroll
    for (int i = 0; i < 4; ++i)
#pragma unroll
      for (int j = 0; j < 4; ++j)
        acc[i][j] = mfma16(afr[i], bfr[j], acc[i][j]);
    __syncthreads();
    cur ^= 1;
  }
#undef STAGE_PL

  float bsv[4]; int ncol[4];
#pragma unroll
  for (int j = 0; j < 4; ++j) {
    ncol[j] = n0 + wn*64 + j*16 + l15;
    bsv[j] = bo[ncol[j]];
  }
#pragma unroll
  for (int i = 0; i < 4; ++i)
#pragma unroll
    for (int rr = 0; rr < 4; ++rr) {
      const int row = m0 + wm*64 + i*16 + 4*lg + rr;
      const float mv = maskF[row];   // query mask
#pragma unroll
      for (int j = 0; j < 4; ++j)
        out[(size_t)row*EE + ncol[j]] = (acc[i][j][rr] + bsv[j]) * mv;
    }
}

// ================= launcher =================
extern "C" void kernel_launch(void* const* d_in, const int* in_sizes, int n_in,
                              void* d_out, int out_size, void* d_ws, size_t ws_size,
                              hipStream_t stream) {
  const float* q  = (const float*)d_in[0];
  const float* k  = (const float*)d_in[1];
  const float* v  = (const float*)d_in[2];
  const float* Wq = (const float*)d_in[3];
  const float* bq = (const float*)d_in[4];
  const float* Wk = (const float*)d_in[5];
  const float* bk = (const float*)d_in[6];
  const float* Wv = (const float*)d_in[7];
  const float* bv = (const float*)d_in[8];
  const float* Wo = (const float*)d_in[9];
  const float* bo = (const float*)d_in[10];
  const float* gq = (const float*)d_in[11];
  const float* betaq = (const float*)d_in[12];
  const float* gk = (const float*)d_in[13];
  const float* betak = (const float*)d_in[14];
  const float* gv = (const float*)d_in[15];
  const float* betav = (const float*)d_in[16];

  char* ws = (char*)d_ws;
  __bf16* Xb = (__bf16*)(ws + oXb);
  __bf16* Wb = (__bf16*)(ws + oWb);
  __bf16* Xh = (__bf16*)(ws + oXh);
  __bf16* AO = (__bf16*)(ws + oAO);
  float*  maskF = (float*)(ws + oMk);

  mask_kernel<<<dim3(96), dim3(256), 0, stream>>>(d_in[17], d_in[18], d_in[19], maskF);
  convert_kernel<<<dim3(13312), dim3(256), 0, stream>>>(q, k, v, Wq, Wk, Wv, Wo, Xb, Wb);
  gemm_proj_ln<<<dim3(64, 4, 3), dim3(256), 0, stream>>>(Xb, Wb, bq, bk, bv,
                                                         gq, betaq, gk, betak, gv, betav,
                                                         maskF, Xh);
  attn_kernel<<<dim3(16, 8, 4), dim3(512), 0, stream>>>(Xh, maskF, AO);
  gemm_out<<<dim3(64, 4, 1), dim3(256), 0, stream>>>(AO, Wb, bo, maskF, (float*)d_out);
}

// Round 13
// 127.384 us; speedup vs baseline: 2.3315x; 1.0017x over previous
//
#include <hip/hip_runtime.h>
#include <cstdint>
#include <cstddef>

// ---------------- problem constants ----------------
#define BB 4
#define SS 2048
#define EE 512
#define HH 8
#define DD 64
#define MM (BB*SS)                       // 8192 token rows
#define BHSD ((size_t)BB*HH*SS*DD)       // 4194304 elements per q/k/v head tensor

static constexpr float SCALE_INV = 1.0f / 181.0f;   // SCALE = float(512 // 8**0.5) = 181.0
static constexpr float LN_EPS = 1e-5f;

typedef float  v4f  __attribute__((ext_vector_type(4)));
typedef __bf16 v8bf __attribute__((ext_vector_type(8)));
typedef __bf16 v4bf __attribute__((ext_vector_type(4)));
typedef short  s4   __attribute__((ext_vector_type(4)));

static __device__ __forceinline__ v4f mfma16(v8bf a, v8bf b, v4f c) {
  return __builtin_amdgcn_mfma_f32_16x16x32_bf16(a, b, c, 0, 0, 0);
}

// async global->LDS, 16B per lane; LDS dest = wave-uniform base + lane*16 (HW rule).
typedef const void __attribute__((address_space(1))) gas_void;
typedef void __attribute__((address_space(3))) las_void;
static __device__ __forceinline__ void gload_lds16(const void* g, void* l) {
  __builtin_amdgcn_global_load_lds((gas_void*)g, (las_void*)l, 16, 0, 0);
}

// ---------------- workspace layout (bytes) ----------------
static constexpr size_t oXb = 0;
static constexpr size_t oWb = oXb + (size_t)3*MM*EE*2;
static constexpr size_t oXh = oWb + (size_t)4*EE*EE*2;
static constexpr size_t oAO = oXh + (size_t)3*MM*EE*2;
static constexpr size_t oMk = oAO + (size_t)MM*EE*2;

// ================= mask canonicalization (parallel) =================
__global__ void mask_kernel(const void* qm, const void* km, const void* vm, float* maskF) {
  __shared__ int s_n01, s_nF;
  const int t = threadIdx.x;
  if (t == 0) { s_n01 = 0; s_nF = 0; }
  __syncthreads();
  int n01 = 0, nF = 0;
  const unsigned* wq = (const unsigned*)qm;
  for (int i = t; i < 2048; i += 256) {
    const unsigned u = wq[i];
    if (u != 0u && u != 1u) n01 = 1;
    if (u != 0u && u != 0x3F800000u) nF = 1;
  }
  if (n01) atomicOr(&s_n01, 1);
  if (nF)  atomicOr(&s_nF, 1);
  __syncthreads();
  const int mode = (!s_n01) ? 0 : (!s_nF) ? 1 : 2;   // 0=i32, 1=f32, 2=u8
  const int gidx = blockIdx.x * 256 + t;
  const int m = gidx / MM, i = gidx % MM;
  const void* p = (m == 0) ? qm : (m == 1) ? km : vm;
  int v;
  if (mode == 0)      v = (((const int*)p)[i] != 0);
  else if (mode == 1) v = (((const unsigned*)p)[i] != 0u);
  else                v = (((const unsigned char*)p)[i] != 0);
  maskF[m*MM + i] = v ? 1.0f : 0.0f;
}

// ================= fp32 -> bf16 convert =================
__global__ void convert_kernel(const float* q, const float* k, const float* v,
                               const float* Wq, const float* Wk, const float* Wv, const float* Wo,
                               __bf16* Xb, __bf16* Wb) {
  const long idx = (long)blockIdx.x * 256 + threadIdx.x;     // in float4 units
  const long NX4 = (long)3*MM*EE/4;
  const long NW4 = (long)4*EE*EE/4;
  if (idx < NX4) {
    const long per = (long)MM*EE/4;
    const long mat = idx / per, off = idx % per;
    const float* src = (mat == 0) ? q : (mat == 1) ? k : v;
    v4f val = ((const v4f*)src)[off];
    v4bf o; o[0]=(__bf16)val[0]; o[1]=(__bf16)val[1]; o[2]=(__bf16)val[2]; o[3]=(__bf16)val[3];
    ((v4bf*)Xb)[idx] = o;
  } else if (idx < NX4 + NW4) {
    const long j = idx - NX4;
    const long per = (long)EE*EE/4;
    const long mat = j / per, off = j % per;
    const float* src = (mat == 0) ? Wq : (mat == 1) ? Wk : (mat == 2) ? Wv : Wo;
    v4f val = ((const v4f*)src)[off];
    v4bf o; o[0]=(__bf16)val[0]; o[1]=(__bf16)val[1]; o[2]=(__bf16)val[2]; o[3]=(__bf16)val[3];
    ((v4bf*)Wb)[j] = o;
  }
}

// ===== projection GEMM + bias + mask + per-head LayerNorm, fused =====
// (unchanged from round 11 -- m97-style 2-phase, passing)
__global__ __launch_bounds__(256) void gemm_proj_ln(const __bf16* Xb, const __bf16* Wb,
                                                    const float* bq, const float* bk, const float* bv,
                                                    const float* gq, const float* betaq,
                                                    const float* gk, const float* betak,
                                                    const float* gv, const float* betav,
                                                    const float* maskF, __bf16* Xh) {
  const int m0  = blockIdx.x * 128;
  const int n0  = blockIdx.y * 128;
  const int mat = blockIdx.z;
  const __bf16* A = Xb + (size_t)mat*MM*EE;
  const __bf16* W = Wb + (size_t)mat*EE*EE;
  const float* bias = (mat == 0) ? bq : (mat == 1) ? bk : bv;
  const float* gam  = (mat == 0) ? gq : (mat == 1) ? gk : gv;
  const float* bet  = (mat == 0) ? betaq : (mat == 1) ? betak : betav;

  __shared__ char smem[32768];   // [buf][A 8KB | B 8KB]

  const int t = threadIdx.x;
  const int lane = t & 63, w = t >> 6;
  const int wm = w >> 1, wn = w & 1;
  const int l15 = lane & 15, lg = lane >> 4;

  v4f acc[4][4];
  const v4f zf = {0.f, 0.f, 0.f, 0.f};
#pragma unroll
  for (int i = 0; i < 4; ++i)
#pragma unroll
    for (int j = 0; j < 4; ++j) acc[i][j] = zf;

  const int sr0 = (w*64 + lane) >> 2;
  const int sct = (w*64 + lane) & 3;
#define STAGE_PL(BUF, KT)                                                                 \
  {                                                                                       \
    char* ab_ = (BUF);                                                                    \
    char* bb_ = (BUF) + 8192;                                                             \
    _Pragma("unroll")                                                                     \
    for (int j_ = 0; j_ < 2; ++j_) {                                                      \
      const int r_ = sr0 + j_*64;                                                         \
      const int c_ = sct ^ (r_ & 3);                                                      \
      gload_lds16(A + (size_t)(m0 + r_)*EE + (KT) + c_*8, ab_ + j_*4096 + w*1024);        \
      gload_lds16(W + (size_t)(n0 + r_)*EE + (KT) + c_*8, bb_ + j_*4096 + w*1024);        \
    }                                                                                     \
  }

  char* buf0 = smem;
  char* buf1 = smem + 16384;

  STAGE_PL(buf0, 0);
  __syncthreads();

  int cur = 0;
  for (int kt = 0; kt < EE; kt += 32) {
    char* cb = cur ? buf1 : buf0;
    char* nb = cur ? buf0 : buf1;
    if (kt + 32 < EE) STAGE_PL(nb, kt + 32);

    const char* As = cb;
    const char* Bs = cb + 8192;
    v8bf afr[4], bfr[4];
#pragma unroll
    for (int i = 0; i < 4; ++i) {
      const int ra = wm*64 + i*16 + l15;
      afr[i] = *(const v8bf*)(As + ra*64 + ((16*lg) ^ ((ra & 3) << 4)));
      const int rb = wn*64 + i*16 + l15;
      bfr[i] = *(const v8bf*)(Bs + rb*64 + ((16*lg) ^ ((rb & 3) << 4)));
    }
#pragma unroll
    for (int i = 0; i < 4; ++i)
#pragma unroll
      for (int j = 0; j < 4; ++j)
        acc[i][j] = mfma16(afr[i], bfr[j], acc[i][j]);
    __syncthreads();
    cur ^= 1;
  }
#undef STAGE_PL

  const int nbase = n0 + wn*64;          // 64-aligned => one head
  const int h = nbase >> 6;
  float bsv[4], gmv[4], btv[4];
#pragma unroll
  for (int j = 0; j < 4; ++j) {
    const int d = j*16 + l15;
    bsv[j] = bias[nbase + d];
    gmv[j] = gam[d];
    btv[j] = bet[d];
  }
#pragma unroll
  for (int i = 0; i < 4; ++i)
#pragma unroll
    for (int rr = 0; rr < 4; ++rr) {
      const int row = m0 + wm*64 + i*16 + 4*lg + rr;
      const float mv = maskF[mat*MM + row];
      float x[4];
      float s = 0.f, s2 = 0.f;
#pragma unroll
      for (int j = 0; j < 4; ++j) {
        x[j] = (acc[i][j][rr] + bsv[j]) * mv;
        s += x[j]; s2 += x[j]*x[j];
      }
      s  += __shfl_xor(s, 1, 64);  s  += __shfl_xor(s, 2, 64);
      s  += __shfl_xor(s, 4, 64);  s  += __shfl_xor(s, 8, 64);
      s2 += __shfl_xor(s2, 1, 64); s2 += __shfl_xor(s2, 2, 64);
      s2 += __shfl_xor(s2, 4, 64); s2 += __shfl_xor(s2, 8, 64);
      const float mu  = s * (1.0f/64.0f);
      const float var = s2 * (1.0f/64.0f) - mu*mu;
      const float rstd = rsqrtf(var + LN_EPS);
      const int bidx = row >> 11, sI = row & 2047;
      if (mat == 2) {
        const size_t vbase = 2*BHSD + (((size_t)bidx*HH + h)*DD)*SS;
#pragma unroll
        for (int j = 0; j < 4; ++j)
          Xh[vbase + (size_t)(j*16 + l15)*SS + sI] = (__bf16)((x[j] - mu)*rstd*gmv[j] + btv[j]);
      } else {
        const size_t base = (size_t)mat*BHSD + (((size_t)bidx*HH + h)*SS + sI)*DD;
#pragma unroll
        for (int j = 0; j < 4; ++j)
          Xh[base + j*16 + l15] = (__bf16)((x[j] - mu)*rstd*gmv[j] + btv[j]);
      }
    }
}

// ================= flash attention: single-buf (4 blocks/CU), K=32 PV via key-perm ======
// grid (16 qb, 8 h, 4 b); block = 512 (8 waves); 33.8KB LDS -> 4 blocks/CU = 32 waves/CU.
// K LDS row r holds global key kt0 + sig(r); after swapped QK^T lane lg holds keys
// g*32+8lg+0..7 across f=2g,2g+1 == the 16x16x32 A-frag layout -> K=32 PV MFMA.
// FIX vs r12: smem = 33,792 B -- the combine overlay is Pp[4][32][65] (33,280 B)
// PLUS Lp[4][32] (512 B). r12 sized smem at exactly 33,280, putting Lp out of
// bounds; CDNA LDS OOB writes are dropped / reads return 0, so lr lost half-1's
// row-sums -> AO 2x too large -> absmax == max|ref| (4.83e-2). One-line fix.
__global__ __launch_bounds__(512) void attn_kernel(const __bf16* Xh, const float* maskF, __bf16* AO) {
  const int qb = blockIdx.x, h = blockIdx.y, b = blockIdx.z;
  const int t = threadIdx.x;
  const int w = t >> 6, lane = t & 63;
  const int hh = w >> 2, wq = w & 3;        // key-half, q-group
  const int l15 = lane & 15, lg = lane >> 4;

  __shared__ char smem[33792];              // staging 2x16KB; overlay Pp(33280)+Lp(512)

  const size_t headoff = (((size_t)b*HH + h)*SS)*DD;
  const __bf16* Qg = Xh + headoff;
  const __bf16* Kg = Xh + BHSD + headoff;
  const __bf16* Vt = Xh + 2*BHSD + (((size_t)b*HH + h)*DD)*SS;   // [D][S]
  const float* qmF = maskF + (size_t)b*SS;
  const float* kmF = maskF + MM + (size_t)b*SS;

  const int q0 = qb*128 + wq*32;

  // Q fragments, pre-scaled by 1/181
  v8bf qf[2][2];
#pragma unroll
  for (int m = 0; m < 2; ++m)
#pragma unroll
    for (int kd = 0; kd < 2; ++kd) {
      v8bf r = *(const v8bf*)(Qg + (size_t)(q0 + m*16 + l15)*DD + kd*32 + lg*8);
      v8bf o;
#pragma unroll
      for (int e = 0; e < 8; ++e) o[e] = (__bf16)((float)r[e] * SCALE_INV);
      qf[m][kd] = o;
    }

  v4f O[2][4];
  float lsum[2] = {0.f, 0.f};
  const v4f zf = {0.f,0.f,0.f,0.f};
#pragma unroll
  for (int m = 0; m < 2; ++m)
#pragma unroll
    for (int df = 0; df < 4; ++df) O[m][df] = zf;

  const int srow = lane >> 3;
  const int sc   = lane & 7;
  // K source row permutation: LDS row r <- global key sig(r).
#define SIGMA(r) (((r) & ~31) | ((((r)>>2)&3)<<3) | ((((r)>>4)&1)<<2) | ((r)&3))
#define STAGE1(BUFC, KT0)                                                                  \
  {                                                                                        \
    char* kb_ = (BUFC);                                                                    \
    char* vb_ = (BUFC) + 8192;                                                             \
    _Pragma("unroll")                                                                      \
    for (int j_ = 0; j_ < 2; ++j_) {                                                       \
      const int r0_ = wq*16 + j_*8;                                                        \
      const int r_  = r0_ + srow;                                                          \
      const int sg_ = SIGMA(r_);                                                           \
      gload_lds16(Kg + (size_t)((KT0) + sg_)*DD + ((sc ^ (r_ & 7))*8), kb_ + r0_*128);     \
      gload_lds16(Vt + (size_t)r_*SS + (KT0) + ((sc ^ (r_ & 7))*8),  vb_ + r0_*128);       \
    }                                                                                      \
  }

  char* buf = smem + hh*16384;

  for (int tt = 0; tt < 16; ++tt) {
    const int kt0 = (tt*2 + hh)*64;
    STAGE1(buf, kt0);
    __syncthreads();              // drains vmcnt -> staged data visible

    char* kb = buf;
    char* vb = buf + 8192;

    // ---- K fragments from LDS (swizzled read; rows hold sig-permuted keys) ----
    v8bf kf[4][2];
#pragma unroll
    for (int f = 0; f < 4; ++f)
#pragma unroll
      for (int kd = 0; kd < 2; ++kd) {
        const int rr = f*16 + l15;
        kf[f][kd] = *(const v8bf*)(kb + rr*128 + (((kd*4 + lg) ^ (rr & 7))*16));
      }

    // ---- S^T = K Q^T : lane q=l15; (f,rr) -> global key kt0+sig(f*16+4lg+rr) ----
    v4f st[2][4];
#pragma unroll
    for (int m = 0; m < 2; ++m)
#pragma unroll
      for (int f = 0; f < 4; ++f) st[m][f] = zf;
#pragma unroll
    for (int kd = 0; kd < 2; ++kd)
#pragma unroll
      for (int f = 0; f < 4; ++f)
#pragma unroll
        for (int m = 0; m < 2; ++m)
          st[m][f] = mfma16(kf[f][kd], qf[m][kd], st[m][f]);

    // key-mask for permuted keys: (f,rr) -> (f>>1)*32 + (f&1)*4 + 8*lg + rr (contig in rr)
    v4f km4[4];
#pragma unroll
    for (int f = 0; f < 4; ++f)
      km4[f] = *(const v4f*)(kmF + kt0 + (f >> 1)*32 + (f & 1)*4 + 8*lg);

    // ---- fixed-max softmax + PV at K=32 ----
#pragma unroll
    for (int m = 0; m < 2; ++m) {
      float p[4][4];
#pragma unroll
      for (int f = 0; f < 4; ++f)
#pragma unroll
        for (int rr = 0; rr < 4; ++rr) {
          p[f][rr] = __expf(st[m][f][rr]) * km4[f][rr];
          lsum[m] += p[f][rr];
        }
#pragma unroll
      for (int g = 0; g < 2; ++g) {
        v8bf pa;
        pa[0] = (__bf16)p[2*g][0];   pa[1] = (__bf16)p[2*g][1];
        pa[2] = (__bf16)p[2*g][2];   pa[3] = (__bf16)p[2*g][3];
        pa[4] = (__bf16)p[2*g+1][0]; pa[5] = (__bf16)p[2*g+1][1];
        pa[6] = (__bf16)p[2*g+1][2]; pa[7] = (__bf16)p[2*g+1][3];
#pragma unroll
        for (int df = 0; df < 4; ++df) {
          const int rv = df*16 + l15;
          v8bf vv = *(const v8bf*)(vb + rv*128 + (((g*4 + lg) ^ (rv & 7))*16));
          O[m][df] = mfma16(pa, vv, O[m][df]);
        }
      }
    }
    __syncthreads();              // all reads done before next stage overwrites
  }
#undef STAGE1
#undef SIGMA

  // ---- per-wave l reduce: row sum for q=l15 valid in all lanes ----
#pragma unroll
  for (int m = 0; m < 2; ++m) {
    lsum[m] += __shfl_xor(lsum[m], 16, 64);
    lsum[m] += __shfl_xor(lsum[m], 32, 64);
  }

  // ---- combine halves in LDS (loop ended with barrier) ----
  float (*Pp)[32][65] = (float (*)[32][65])smem;            // [4][32][65] = 33,280 B
  float (*Lp)[32]     = (float (*)[32])(smem + 4*32*65*4);  // +512 B (in bounds now)
  if (hh == 1) {
#pragma unroll
    for (int m = 0; m < 2; ++m)
#pragma unroll
      for (int df = 0; df < 4; ++df)
#pragma unroll
        for (int rr = 0; rr < 4; ++rr)
          Pp[wq][m*16 + 4*lg + rr][df*16 + l15] = O[m][df][rr];
    if (lg == 0) { Lp[wq][l15] = lsum[0]; Lp[wq][16 + l15] = lsum[1]; }
  }
  __syncthreads();
  if (hh == 0) {
#pragma unroll
    for (int m = 0; m < 2; ++m) {
      lsum[m] += Lp[wq][m*16 + l15];
#pragma unroll
      for (int df = 0; df < 4; ++df)
#pragma unroll
        for (int rr = 0; rr < 4; ++rr)
          O[m][df][rr] += Pp[wq][m*16 + 4*lg + rr][df*16 + l15];
    }
#pragma unroll
    for (int m = 0; m < 2; ++m)
#pragma unroll
      for (int rr = 0; rr < 4; ++rr) {
        const float lr = __shfl(lsum[m], (lg << 4) | (4*lg + rr), 64);
        const int qrow = q0 + m*16 + 4*lg + rr;
        const float scl = qmF[qrow] / fmaxf(lr, 1e-30f);
#pragma unroll
        for (int df = 0; df < 4; ++df)
          AO[(size_t)(b*SS + qrow)*EE + h*DD + df*16 + l15] = (__bf16)(O[m][df][rr] * scl);
      }
  }
}

// ================= output GEMM: out = (AO @ Wo^T + bo) * qmask =================
// (unchanged from round 11)
__global__ __launch_bounds__(256) void gemm_out(const __bf16* AO, const __bf16* Wb,
                                                const float* bo, const float* maskF, float* out) {
  const int m0 = blockIdx.x * 128;
  const int n0 = blockIdx.y * 128;
  const __bf16* A = AO;
  const __bf16* W = Wb + (size_t)3*EE*EE;   // Wo

  __shared__ char smem[32768];

  const int t = threadIdx.x;
  const int lane = t & 63, w = t >> 6;
  const int wm = w >> 1, wn = w & 1;
  const int l15 = lane & 15, lg = lane >> 4;

  v4f acc[4][4];
  const v4f zf = {0.f,0.f,0.f,0.f};
#pragma unroll
  for (int i = 0; i < 4; ++i)
#pragma unroll
    for (int j = 0; j < 4; ++j) acc[i][j] = zf;

  const int sr0 = (w*64 + lane) >> 2;
  const int sct = (w*64 + lane) & 3;
#define STAGE_PL(BUF, KT)                                                                 \
  {                                                                                       \
    char* ab_ = (BUF);                                                                    \
    char* bb_ = (BUF) + 8192;                                                             \
    _Pragma("unroll")                                                                     \
    for (int j_ = 0; j_ < 2; ++j_) {                                                      \
      const int r_ = sr0 + j_*64;                                                         \
      const int c_ = sct ^ (r_ & 3);                                                      \
      gload_lds16(A + (size_t)(m0 + r_)*EE + (KT) + c_*8, ab_ + j_*4096 + w*1024);        \
      gload_lds16(W + (size_t)(n0 + r_)*EE + (KT) + c_*8, bb_ + j_*4096 + w*1024);        \
    }                                                                                     \
  }

  char* buf0 = smem;
  char* buf1 = smem + 16384;

  STAGE_PL(buf0, 0);
  __syncthreads();

  int cur = 0;
  for (int kt = 0; kt < EE; kt += 32) {
    char* cb = cur ? buf1 : buf0;
    char* nb = cur ? buf0 : buf1;
    if (kt + 32 < EE) STAGE_PL(nb, kt + 32);

    const char* As = cb;
    const char* Bs = cb + 8192;
    v8bf afr[4], bfr[4];
#pragma unroll
    for (int i = 0; i < 4; ++i) {
      const int ra = wm*64 + i*16 + l15;
      afr[i] = *(const v8bf*)(As + ra*64 + ((16*lg) ^ ((ra & 3) << 4)));
      const int rb = wn*64 + i*16 + l15;
      bfr[i] = *(const v8bf*)(Bs + rb*64 + ((16*lg) ^ ((rb & 3) << 4)));
    }
#pragma unroll
    for (int i = 0; i < 4; ++i)
#pragma unroll
      for (int j = 0; j < 4; ++j)
        acc[i][j] = mfma16(afr[i], bfr[j], acc[i][j]);
    __syncthreads();
    cur ^= 1;
  }
#undef STAGE_PL

  float bsv[4]; int ncol[4];
#pragma unroll
  for (int j = 0; j < 4; ++j) {
    ncol[j] = n0 + wn*64 + j*16 + l15;
    bsv[j] = bo[ncol[j]];
  }
#pragma unroll
  for (int i = 0; i < 4; ++i)
#pragma unroll
    for (int rr = 0; rr < 4; ++rr) {
      const int row = m0 + wm*64 + i*16 + 4*lg + rr;
      const float mv = maskF[row];   // query mask
#pragma unroll
      for (int j = 0; j < 4; ++j)
        out[(size_t)row*EE + ncol[j]] = (acc[i][j][rr] + bsv[j]) * mv;
    }
}

// ================= launcher =================
extern "C" void kernel_launch(void* const* d_in, const int* in_sizes, int n_in,
                              void* d_out, int out_size, void* d_ws, size_t ws_size,
                              hipStream_t stream) {
  const float* q  = (const float*)d_in[0];
  const float* k  = (const float*)d_in[1];
  const float* v  = (const float*)d_in[2];
  const float* Wq = (const float*)d_in[3];
  const float* bq = (const float*)d_in[4];
  const float* Wk = (const float*)d_in[5];
  const float* bk = (const float*)d_in[6];
  const float* Wv = (const float*)d_in[7];
  const float* bv = (const float*)d_in[8];
  const float* Wo = (const float*)d_in[9];
  const float* bo = (const float*)d_in[10];
  const float* gq = (const float*)d_in[11];
  const float* betaq = (const float*)d_in[12];
  const float* gk = (const float*)d_in[13];
  const float* betak = (const float*)d_in[14];
  const float* gv = (const float*)d_in[15];
  const float* betav = (const float*)d_in[16];

  char* ws = (char*)d_ws;
  __bf16* Xb = (__bf16*)(ws + oXb);
  __bf16* Wb = (__bf16*)(ws + oWb);
  __bf16* Xh = (__bf16*)(ws + oXh);
  __bf16* AO = (__bf16*)(ws + oAO);
  float*  maskF = (float*)(ws + oMk);

  mask_kernel<<<dim3(96), dim3(256), 0, stream>>>(d_in[17], d_in[18], d_in[19], maskF);
  convert_kernel<<<dim3(13312), dim3(256), 0, stream>>>(q, k, v, Wq, Wk, Wv, Wo, Xb, Wb);
  gemm_proj_ln<<<dim3(64, 4, 3), dim3(256), 0, stream>>>(Xb, Wb, bq, bk, bv,
                                                         gq, betaq, gk, betak, gv, betav,
                                                         maskF, Xh);
  attn_kernel<<<dim3(16, 8, 4), dim3(512), 0, stream>>>(Xh, maskF, AO);
  gemm_out<<<dim3(64, 4, 1), dim3(256), 0, stream>>>(AO, Wb, bo, maskF, (float*)d_out);
}

// Round 14
// 116.124 us; speedup vs baseline: 2.5576x; 1.0970x over previous
//
#include <hip/hip_runtime.h>
#include <cstdint>
#include <cstddef>

// ---------------- problem constants ----------------
#define BB 4
#define SS 2048
#define EE 512
#define HH 8
#define DD 64
#define MM (BB*SS)                       // 8192 token rows
#define BHSD ((size_t)BB*HH*SS*DD)       // 4194304 elements per q/k/v head tensor

static constexpr float SCALE_INV = 1.0f / 181.0f;   // SCALE = float(512 // 8**0.5) = 181.0
static constexpr float LN_EPS = 1e-5f;

typedef float  v4f  __attribute__((ext_vector_type(4)));
typedef __bf16 v8bf __attribute__((ext_vector_type(8)));
typedef __bf16 v4bf __attribute__((ext_vector_type(4)));
typedef short  s4   __attribute__((ext_vector_type(4)));

static __device__ __forceinline__ v4f mfma16(v8bf a, v8bf b, v4f c) {
  return __builtin_amdgcn_mfma_f32_16x16x32_bf16(a, b, c, 0, 0, 0);
}

// async global->LDS, 16B per lane; LDS dest = wave-uniform base + lane*16 (HW rule).
typedef const void __attribute__((address_space(1))) gas_void;
typedef void __attribute__((address_space(3))) las_void;
static __device__ __forceinline__ void gload_lds16(const void* g, void* l) {
  __builtin_amdgcn_global_load_lds((gas_void*)g, (las_void*)l, 16, 0, 0);
}

// ---------------- workspace layout (bytes) ----------------
static constexpr size_t oXb = 0;
static constexpr size_t oWb = oXb + (size_t)3*MM*EE*2;
static constexpr size_t oXh = oWb + (size_t)4*EE*EE*2;
static constexpr size_t oAO = oXh + (size_t)3*MM*EE*2;
static constexpr size_t oMk = oAO + (size_t)MM*EE*2;

// ================= mask canonicalization (parallel) =================
__global__ void mask_kernel(const void* qm, const void* km, const void* vm, float* maskF) {
  __shared__ int s_n01, s_nF;
  const int t = threadIdx.x;
  if (t == 0) { s_n01 = 0; s_nF = 0; }
  __syncthreads();
  int n01 = 0, nF = 0;
  const unsigned* wq = (const unsigned*)qm;
  for (int i = t; i < 2048; i += 256) {
    const unsigned u = wq[i];
    if (u != 0u && u != 1u) n01 = 1;
    if (u != 0u && u != 0x3F800000u) nF = 1;
  }
  if (n01) atomicOr(&s_n01, 1);
  if (nF)  atomicOr(&s_nF, 1);
  __syncthreads();
  const int mode = (!s_n01) ? 0 : (!s_nF) ? 1 : 2;   // 0=i32, 1=f32, 2=u8
  const int gidx = blockIdx.x * 256 + t;
  const int m = gidx / MM, i = gidx % MM;
  const void* p = (m == 0) ? qm : (m == 1) ? km : vm;
  int v;
  if (mode == 0)      v = (((const int*)p)[i] != 0);
  else if (mode == 1) v = (((const unsigned*)p)[i] != 0u);
  else                v = (((const unsigned char*)p)[i] != 0);
  maskF[m*MM + i] = v ? 1.0f : 0.0f;
}

// ================= fp32 -> bf16 convert =================
__global__ void convert_kernel(const float* q, const float* k, const float* v,
                               const float* Wq, const float* Wk, const float* Wv, const float* Wo,
                               __bf16* Xb, __bf16* Wb) {
  const long idx = (long)blockIdx.x * 256 + threadIdx.x;     // in float4 units
  const long NX4 = (long)3*MM*EE/4;
  const long NW4 = (long)4*EE*EE/4;
  if (idx < NX4) {
    const long per = (long)MM*EE/4;
    const long mat = idx / per, off = idx % per;
    const float* src = (mat == 0) ? q : (mat == 1) ? k : v;
    v4f val = ((const v4f*)src)[off];
    v4bf o; o[0]=(__bf16)val[0]; o[1]=(__bf16)val[1]; o[2]=(__bf16)val[2]; o[3]=(__bf16)val[3];
    ((v4bf*)Xb)[idx] = o;
  } else if (idx < NX4 + NW4) {
    const long j = idx - NX4;
    const long per = (long)EE*EE/4;
    const long mat = j / per, off = j % per;
    const float* src = (mat == 0) ? Wq : (mat == 1) ? Wk : (mat == 2) ? Wv : Wo;
    v4f val = ((const v4f*)src)[off];
    v4bf o; o[0]=(__bf16)val[0]; o[1]=(__bf16)val[1]; o[2]=(__bf16)val[2]; o[3]=(__bf16)val[3];
    ((v4bf*)Wb)[j] = o;
  }
}

// ===== projection GEMM + bias + mask + per-head LayerNorm, fused =====
// (unchanged from round 11 -- m97-style 2-phase, passing)
__global__ __launch_bounds__(256) void gemm_proj_ln(const __bf16* Xb, const __bf16* Wb,
                                                    const float* bq, const float* bk, const float* bv,
                                                    const float* gq, const float* betaq,
                                                    const float* gk, const float* betak,
                                                    const float* gv, const float* betav,
                                                    const float* maskF, __bf16* Xh) {
  const int m0  = blockIdx.x * 128;
  const int n0  = blockIdx.y * 128;
  const int mat = blockIdx.z;
  const __bf16* A = Xb + (size_t)mat*MM*EE;
  const __bf16* W = Wb + (size_t)mat*EE*EE;
  const float* bias = (mat == 0) ? bq : (mat == 1) ? bk : bv;
  const float* gam  = (mat == 0) ? gq : (mat == 1) ? gk : gv;
  const float* bet  = (mat == 0) ? betaq : (mat == 1) ? betak : betav;

  __shared__ char smem[32768];   // [buf][A 8KB | B 8KB]

  const int t = threadIdx.x;
  const int lane = t & 63, w = t >> 6;
  const int wm = w >> 1, wn = w & 1;
  const int l15 = lane & 15, lg = lane >> 4;

  v4f acc[4][4];
  const v4f zf = {0.f, 0.f, 0.f, 0.f};
#pragma unroll
  for (int i = 0; i < 4; ++i)
#pragma unroll
    for (int j = 0; j < 4; ++j) acc[i][j] = zf;

  const int sr0 = (w*64 + lane) >> 2;
  const int sct = (w*64 + lane) & 3;
#define STAGE_PL(BUF, KT)                                                                 \
  {                                                                                       \
    char* ab_ = (BUF);                                                                    \
    char* bb_ = (BUF) + 8192;                                                             \
    _Pragma("unroll")                                                                     \
    for (int j_ = 0; j_ < 2; ++j_) {                                                      \
      const int r_ = sr0 + j_*64;                                                         \
      const int c_ = sct ^ (r_ & 3);                                                      \
      gload_lds16(A + (size_t)(m0 + r_)*EE + (KT) + c_*8, ab_ + j_*4096 + w*1024);        \
      gload_lds16(W + (size_t)(n0 + r_)*EE + (KT) + c_*8, bb_ + j_*4096 + w*1024);        \
    }                                                                                     \
  }

  char* buf0 = smem;
  char* buf1 = smem + 16384;

  STAGE_PL(buf0, 0);
  __syncthreads();

  int cur = 0;
  for (int kt = 0; kt < EE; kt += 32) {
    char* cb = cur ? buf1 : buf0;
    char* nb = cur ? buf0 : buf1;
    if (kt + 32 < EE) STAGE_PL(nb, kt + 32);

    const char* As = cb;
    const char* Bs = cb + 8192;
    v8bf afr[4], bfr[4];
#pragma unroll
    for (int i = 0; i < 4; ++i) {
      const int ra = wm*64 + i*16 + l15;
      afr[i] = *(const v8bf*)(As + ra*64 + ((16*lg) ^ ((ra & 3) << 4)));
      const int rb = wn*64 + i*16 + l15;
      bfr[i] = *(const v8bf*)(Bs + rb*64 + ((16*lg) ^ ((rb & 3) << 4)));
    }
#pragma unroll
    for (int i = 0; i < 4; ++i)
#pragma unroll
      for (int j = 0; j < 4; ++j)
        acc[i][j] = mfma16(afr[i], bfr[j], acc[i][j]);
    __syncthreads();
    cur ^= 1;
  }
#undef STAGE_PL

  const int nbase = n0 + wn*64;          // 64-aligned => one head
  const int h = nbase >> 6;
  float bsv[4], gmv[4], btv[4];
#pragma unroll
  for (int j = 0; j < 4; ++j) {
    const int d = j*16 + l15;
    bsv[j] = bias[nbase + d];
    gmv[j] = gam[d];
    btv[j] = bet[d];
  }
#pragma unroll
  for (int i = 0; i < 4; ++i)
#pragma unroll
    for (int rr = 0; rr < 4; ++rr) {
      const int row = m0 + wm*64 + i*16 + 4*lg + rr;
      const float mv = maskF[mat*MM + row];
      float x[4];
      float s = 0.f, s2 = 0.f;
#pragma unroll
      for (int j = 0; j < 4; ++j) {
        x[j] = (acc[i][j][rr] + bsv[j]) * mv;
        s += x[j]; s2 += x[j]*x[j];
      }
      s  += __shfl_xor(s, 1, 64);  s  += __shfl_xor(s, 2, 64);
      s  += __shfl_xor(s, 4, 64);  s  += __shfl_xor(s, 8, 64);
      s2 += __shfl_xor(s2, 1, 64); s2 += __shfl_xor(s2, 2, 64);
      s2 += __shfl_xor(s2, 4, 64); s2 += __shfl_xor(s2, 8, 64);
      const float mu  = s * (1.0f/64.0f);
      const float var = s2 * (1.0f/64.0f) - mu*mu;
      const float rstd = rsqrtf(var + LN_EPS);
      const int bidx = row >> 11, sI = row & 2047;
      if (mat == 2) {
        const size_t vbase = 2*BHSD + (((size_t)bidx*HH + h)*DD)*SS;
#pragma unroll
        for (int j = 0; j < 4; ++j)
          Xh[vbase + (size_t)(j*16 + l15)*SS + sI] = (__bf16)((x[j] - mu)*rstd*gmv[j] + btv[j]);
      } else {
        const size_t base = (size_t)mat*BHSD + (((size_t)bidx*HH + h)*SS + sI)*DD;
#pragma unroll
        for (int j = 0; j < 4; ++j)
          Xh[base + j*16 + l15] = (__bf16)((x[j] - mu)*rstd*gmv[j] + btv[j]);
      }
    }
}

// ================= flash attention: dbuf + K=32 PV via key-perm (r11 pipe + r13 math) ====
// grid (16 qb, 8 h, 4 b); block = 512 (8 waves). Waves 0-3 even key tiles, 4-7 odd.
// Double-buffered staging ([half][2 bufs] = 64KB; grid gives 2 blocks/CU so 64KB is
// free). STAGE(next) issues before compute(cur): HBM latency hides under compute;
// the end-of-iter barrier drains it after compute. K LDS row r holds key sig(r)
// (within-32 bit-shuffle) so PV runs at K=32 (r13-verified); bank conflicts 262K.
// Fixed-max softmax (r9-proven); combine overlay Pp(33280)+Lp(512) fits in 64KB.
__global__ __launch_bounds__(512) void attn_kernel(const __bf16* Xh, const float* maskF, __bf16* AO) {
  const int qb = blockIdx.x, h = blockIdx.y, b = blockIdx.z;
  const int t = threadIdx.x;
  const int w = t >> 6, lane = t & 63;
  const int hh = w >> 2, wq = w & 3;        // key-half, q-group
  const int l15 = lane & 15, lg = lane >> 4;

  __shared__ char smem[65536];              // [half][buf]{K 8KB, V 8KB} + overlay

  const size_t headoff = (((size_t)b*HH + h)*SS)*DD;
  const __bf16* Qg = Xh + headoff;
  const __bf16* Kg = Xh + BHSD + headoff;
  const __bf16* Vt = Xh + 2*BHSD + (((size_t)b*HH + h)*DD)*SS;   // [D][S]
  const float* qmF = maskF + (size_t)b*SS;
  const float* kmF = maskF + MM + (size_t)b*SS;

  const int q0 = qb*128 + wq*32;

  // Q fragments, pre-scaled by 1/181
  v8bf qf[2][2];
#pragma unroll
  for (int m = 0; m < 2; ++m)
#pragma unroll
    for (int kd = 0; kd < 2; ++kd) {
      v8bf r = *(const v8bf*)(Qg + (size_t)(q0 + m*16 + l15)*DD + kd*32 + lg*8);
      v8bf o;
#pragma unroll
      for (int e = 0; e < 8; ++e) o[e] = (__bf16)((float)r[e] * SCALE_INV);
      qf[m][kd] = o;
    }

  v4f O[2][4];
  float lsum[2] = {0.f, 0.f};
  const v4f zf = {0.f,0.f,0.f,0.f};
#pragma unroll
  for (int m = 0; m < 2; ++m)
#pragma unroll
    for (int df = 0; df < 4; ++df) O[m][df] = zf;

  const int srow = lane >> 3;
  const int sc   = lane & 7;
  // K source row permutation: LDS row r <- global key sig(r).
#define SIGMA(r) (((r) & ~31) | ((((r)>>2)&3)<<3) | ((((r)>>4)&1)<<2) | ((r)&3))
#define STAGE1(BUFC, KT0)                                                                  \
  {                                                                                        \
    char* kb_ = (BUFC);                                                                    \
    char* vb_ = (BUFC) + 8192;                                                             \
    _Pragma("unroll")                                                                      \
    for (int j_ = 0; j_ < 2; ++j_) {                                                       \
      const int r0_ = wq*16 + j_*8;                                                        \
      const int r_  = r0_ + srow;                                                          \
      const int sg_ = SIGMA(r_);                                                           \
      gload_lds16(Kg + (size_t)((KT0) + sg_)*DD + ((sc ^ (r_ & 7))*8), kb_ + r0_*128);     \
      gload_lds16(Vt + (size_t)r_*SS + (KT0) + ((sc ^ (r_ & 7))*8),  vb_ + r0_*128);       \
    }                                                                                      \
  }

  char* bufA = smem + hh*32768;
  char* bufB = bufA + 16384;

  STAGE1(bufA, hh*64);
  __syncthreads();

  for (int tt = 0; tt < 16; ++tt) {
    char* cur = (tt & 1) ? bufB : bufA;
    char* nxt = (tt & 1) ? bufA : bufB;
    if (tt + 1 < 16) STAGE1(nxt, ((tt+1)*2 + hh)*64);   // hides under compute(cur)

    const int kt0 = (tt*2 + hh)*64;
    char* kb = cur;
    char* vb = cur + 8192;

    // ---- K fragments from LDS (swizzled read; rows hold sig-permuted keys) ----
    v8bf kf[4][2];
#pragma unroll
    for (int f = 0; f < 4; ++f)
#pragma unroll
      for (int kd = 0; kd < 2; ++kd) {
        const int rr = f*16 + l15;
        kf[f][kd] = *(const v8bf*)(kb + rr*128 + (((kd*4 + lg) ^ (rr & 7))*16));
      }

    // ---- S^T = K Q^T : lane q=l15; (f,rr) -> global key kt0+sig(f*16+4lg+rr) ----
    v4f st[2][4];
#pragma unroll
    for (int m = 0; m < 2; ++m)
#pragma unroll
      for (int f = 0; f < 4; ++f) st[m][f] = zf;
#pragma unroll
    for (int kd = 0; kd < 2; ++kd)
#pragma unroll
      for (int f = 0; f < 4; ++f)
#pragma unroll
        for (int m = 0; m < 2; ++m)
          st[m][f] = mfma16(kf[f][kd], qf[m][kd], st[m][f]);

    // key-mask for permuted keys: (f,rr) -> (f>>1)*32 + (f&1)*4 + 8*lg + rr (contig in rr)
    v4f km4[4];
#pragma unroll
    for (int f = 0; f < 4; ++f)
      km4[f] = *(const v4f*)(kmF + kt0 + (f >> 1)*32 + (f & 1)*4 + 8*lg);

    // ---- fixed-max softmax + PV at K=32 ----
#pragma unroll
    for (int m = 0; m < 2; ++m) {
      float p[4][4];
#pragma unroll
      for (int f = 0; f < 4; ++f)
#pragma unroll
        for (int rr = 0; rr < 4; ++rr) {
          p[f][rr] = __expf(st[m][f][rr]) * km4[f][rr];
          lsum[m] += p[f][rr];
        }
#pragma unroll
      for (int g = 0; g < 2; ++g) {
        v8bf pa;
        pa[0] = (__bf16)p[2*g][0];   pa[1] = (__bf16)p[2*g][1];
        pa[2] = (__bf16)p[2*g][2];   pa[3] = (__bf16)p[2*g][3];
        pa[4] = (__bf16)p[2*g+1][0]; pa[5] = (__bf16)p[2*g+1][1];
        pa[6] = (__bf16)p[2*g+1][2]; pa[7] = (__bf16)p[2*g+1][3];
#pragma unroll
        for (int df = 0; df < 4; ++df) {
          const int rv = df*16 + l15;
          v8bf vv = *(const v8bf*)(vb + rv*128 + (((g*4 + lg) ^ (rv & 7))*16));
          O[m][df] = mfma16(pa, vv, O[m][df]);
        }
      }
    }
    __syncthreads();   // drains stage(next); protects cur overwrite at tt+2
  }
#undef STAGE1
#undef SIGMA

  // ---- per-wave l reduce: row sum for q=l15 valid in all lanes ----
#pragma unroll
  for (int m = 0; m < 2; ++m) {
    lsum[m] += __shfl_xor(lsum[m], 16, 64);
    lsum[m] += __shfl_xor(lsum[m], 32, 64);
  }

  // ---- combine halves in LDS (loop ended with barrier) ----
  float (*Pp)[32][65] = (float (*)[32][65])smem;            // [4][32][65] = 33,280 B
  float (*Lp)[32]     = (float (*)[32])(smem + 4*32*65*4);  // +512 B
  if (hh == 1) {
#pragma unroll
    for (int m = 0; m < 2; ++m)
#pragma unroll
      for (int df = 0; df < 4; ++df)
#pragma unroll
        for (int rr = 0; rr < 4; ++rr)
          Pp[wq][m*16 + 4*lg + rr][df*16 + l15] = O[m][df][rr];
    if (lg == 0) { Lp[wq][l15] = lsum[0]; Lp[wq][16 + l15] = lsum[1]; }
  }
  __syncthreads();
  if (hh == 0) {
#pragma unroll
    for (int m = 0; m < 2; ++m) {
      lsum[m] += Lp[wq][m*16 + l15];
#pragma unroll
      for (int df = 0; df < 4; ++df)
#pragma unroll
        for (int rr = 0; rr < 4; ++rr)
          O[m][df][rr] += Pp[wq][m*16 + 4*lg + rr][df*16 + l15];
    }
#pragma unroll
    for (int m = 0; m < 2; ++m)
#pragma unroll
      for (int rr = 0; rr < 4; ++rr) {
        const float lr = __shfl(lsum[m], (lg << 4) | (4*lg + rr), 64);
        const int qrow = q0 + m*16 + 4*lg + rr;
        const float scl = qmF[qrow] / fmaxf(lr, 1e-30f);
#pragma unroll
        for (int df = 0; df < 4; ++df)
          AO[(size_t)(b*SS + qrow)*EE + h*DD + df*16 + l15] = (__bf16)(O[m][df][rr] * scl);
      }
  }
}

// ================= output GEMM: out = (AO @ Wo^T + bo) * qmask =================
// (unchanged from round 11)
__global__ __launch_bounds__(256) void gemm_out(const __bf16* AO, const __bf16* Wb,
                                                const float* bo, const float* maskF, float* out) {
  const int m0 = blockIdx.x * 128;
  const int n0 = blockIdx.y * 128;
  const __bf16* A = AO;
  const __bf16* W = Wb + (size_t)3*EE*EE;   // Wo

  __shared__ char smem[32768];

  const int t = threadIdx.x;
  const int lane = t & 63, w = t >> 6;
  const int wm = w >> 1, wn = w & 1;
  const int l15 = lane & 15, lg = lane >> 4;

  v4f acc[4][4];
  const v4f zf = {0.f,0.f,0.f,0.f};
#pragma unroll
  for (int i = 0; i < 4; ++i)
#pragma unroll
    for (int j = 0; j < 4; ++j) acc[i][j] = zf;

  const int sr0 = (w*64 + lane) >> 2;
  const int sct = (w*64 + lane) & 3;
#define STAGE_PL(BUF, KT)                                                                 \
  {                                                                                       \
    char* ab_ = (BUF);                                                                    \
    char* bb_ = (BUF) + 8192;                                                             \
    _Pragma("unroll")                                                                     \
    for (int j_ = 0; j_ < 2; ++j_) {                                                      \
      const int r_ = sr0 + j_*64;                                                         \
      const int c_ = sct ^ (r_ & 3);                                                      \
      gload_lds16(A + (size_t)(m0 + r_)*EE + (KT) + c_*8, ab_ + j_*4096 + w*1024);        \
      gload_lds16(W + (size_t)(n0 + r_)*EE + (KT) + c_*8, bb_ + j_*4096 + w*1024);        \
    }                                                                                     \
  }

  char* buf0 = smem;
  char* buf1 = smem + 16384;

  STAGE_PL(buf0, 0);
  __syncthreads();

  int cur = 0;
  for (int kt = 0; kt < EE; kt += 32) {
    char* cb = cur ? buf1 : buf0;
    char* nb = cur ? buf0 : buf1;
    if (kt + 32 < EE) STAGE_PL(nb, kt + 32);

    const char* As = cb;
    const char* Bs = cb + 8192;
    v8bf afr[4], bfr[4];
#pragma unroll
    for (int i = 0; i < 4; ++i) {
      const int ra = wm*64 + i*16 + l15;
      afr[i] = *(const v8bf*)(As + ra*64 + ((16*lg) ^ ((ra & 3) << 4)));
      const int rb = wn*64 + i*16 + l15;
      bfr[i] = *(const v8bf*)(Bs + rb*64 + ((16*lg) ^ ((rb & 3) << 4)));
    }
#pragma unroll
    for (int i = 0; i < 4; ++i)
#pragma unroll
      for (int j = 0; j < 4; ++j)
        acc[i][j] = mfma16(afr[i], bfr[j], acc[i][j]);
    __syncthreads();
    cur ^= 1;
  }
#undef STAGE_PL

  float bsv[4]; int ncol[4];
#pragma unroll
  for (int j = 0; j < 4; ++j) {
    ncol[j] = n0 + wn*64 + j*16 + l15;
    bsv[j] = bo[ncol[j]];
  }
#pragma unroll
  for (int i = 0; i < 4; ++i)
#pragma unroll
    for (int rr = 0; rr < 4; ++rr) {
      const int row = m0 + wm*64 + i*16 + 4*lg + rr;
      const float mv = maskF[row];   // query mask
#pragma unroll
      for (int j = 0; j < 4; ++j)
        out[(size_t)row*EE + ncol[j]] = (acc[i][j][rr] + bsv[j]) * mv;
    }
}

// ================= launcher =================
extern "C" void kernel_launch(void* const* d_in, const int* in_sizes, int n_in,
                              void* d_out, int out_size, void* d_ws, size_t ws_size,
                              hipStream_t stream) {
  const float* q  = (const float*)d_in[0];
  const float* k  = (const float*)d_in[1];
  const float* v  = (const float*)d_in[2];
  const float* Wq = (const float*)d_in[3];
  const float* bq = (const float*)d_in[4];
  const float* Wk = (const float*)d_in[5];
  const float* bk = (const float*)d_in[6];
  const float* Wv = (const float*)d_in[7];
  const float* bv = (const float*)d_in[8];
  const float* Wo = (const float*)d_in[9];
  const float* bo = (const float*)d_in[10];
  const float* gq = (const float*)d_in[11];
  const float* betaq = (const float*)d_in[12];
  const float* gk = (const float*)d_in[13];
  const float* betak = (const float*)d_in[14];
  const float* gv = (const float*)d_in[15];
  const float* betav = (const float*)d_in[16];

  char* ws = (char*)d_ws;
  __bf16* Xb = (__bf16*)(ws + oXb);
  __bf16* Wb = (__bf16*)(ws + oWb);
  __bf16* Xh = (__bf16*)(ws + oXh);
  __bf16* AO = (__bf16*)(ws + oAO);
  float*  maskF = (float*)(ws + oMk);

  mask_kernel<<<dim3(96), dim3(256), 0, stream>>>(d_in[17], d_in[18], d_in[19], maskF);
  convert_kernel<<<dim3(13312), dim3(256), 0, stream>>>(q, k, v, Wq, Wk, Wv, Wo, Xb, Wb);
  gemm_proj_ln<<<dim3(64, 4, 3), dim3(256), 0, stream>>>(Xb, Wb, bq, bk, bv,
                                                         gq, betaq, gk, betak, gv, betav,
                                                         maskF, Xh);
  attn_kernel<<<dim3(16, 8, 4), dim3(512), 0, stream>>>(Xh, maskF, AO);
  gemm_out<<<dim3(64, 4, 1), dim3(256), 0, stream>>>(AO, Wb, bo, maskF, (float*)d_out);
}